// Round 8
// baseline (159.212 us; speedup 1.0000x reference)
//
#include <hip/hip_runtime.h>

// Problem constants
#define S_LEN 4096
#define DMODEL 768
#define NHEAD 12
#define HDIM 64
#define DQKV 2304

typedef __attribute__((ext_vector_type(8))) __bf16 bf16x8;
typedef __attribute__((ext_vector_type(4))) float f32x4;
typedef __attribute__((ext_vector_type(8))) unsigned short ushort8;

#define LOG2E 1.4426950408889634f

#if __has_builtin(__builtin_amdgcn_exp2f)
#define EXP2(x) __builtin_amdgcn_exp2f(x)
#else
#define EXP2(x) exp2f(x)
#endif

static __device__ __forceinline__ unsigned short f2bf(float f) {
  unsigned int u = __float_as_uint(f);
  u += 0x7FFFu + ((u >> 16) & 1u);  // round-to-nearest-even
  return (unsigned short)(u >> 16);
}

// async global -> LDS, 16B per lane. Dest must be wave-uniform; HW writes
// lptr + lane*16. Global src is per-lane (contiguous here -> coalesced).
static __device__ __forceinline__ void gload_lds16(const unsigned short* g, unsigned short* l) {
  __builtin_amdgcn_global_load_lds(
      (const __attribute__((address_space(1))) unsigned int*)g,
      (__attribute__((address_space(3))) unsigned int*)l, 16, 0, 0);
}

// ---------------------------------------------------------------------------
// fp32 -> bf16 elementwise convert (n must be multiple of 8)
// ---------------------------------------------------------------------------
__global__ __launch_bounds__(256) void k_convert(const float* __restrict__ in,
                                                 unsigned short* __restrict__ out,
                                                 int n) {
  int i = (blockIdx.x * 256 + threadIdx.x) * 8;
  if (i >= n) return;
  const float4* p = reinterpret_cast<const float4*>(in + i);
  float4 a = p[0], b = p[1];
  ushort8 r;
  r[0] = f2bf(a.x); r[1] = f2bf(a.y); r[2] = f2bf(a.z); r[3] = f2bf(a.w);
  r[4] = f2bf(b.x); r[5] = f2bf(b.y); r[6] = f2bf(b.z); r[7] = f2bf(b.w);
  *reinterpret_cast<ushort8*>(out + i) = r;
}

// ---------------------------------------------------------------------------
// [K][N] fp32  ->  [N][K] bf16 transpose-convert, 64x64 tiles
// ---------------------------------------------------------------------------
__global__ __launch_bounds__(256) void k_transpose(const float* __restrict__ in,
                                                   unsigned short* __restrict__ out,
                                                   int Kdim, int Ndim) {
  __shared__ unsigned short t[64 * 65];
  int k0 = blockIdx.y * 64, n0 = blockIdx.x * 64;
  int tid = threadIdx.x;
#pragma unroll
  for (int p = 0; p < 4; ++p) {
    int r = p * 16 + (tid >> 4);   // k offset in tile
    int c = (tid & 15) * 4;        // n offset in tile
    float4 v = *reinterpret_cast<const float4*>(in + (size_t)(k0 + r) * Ndim + n0 + c);
    t[(c + 0) * 65 + r] = f2bf(v.x);
    t[(c + 1) * 65 + r] = f2bf(v.y);
    t[(c + 2) * 65 + r] = f2bf(v.z);
    t[(c + 3) * 65 + r] = f2bf(v.w);
  }
  __syncthreads();
#pragma unroll
  for (int p = 0; p < 2; ++p) {
    int task = p * 256 + tid;
    int rr = task >> 3;        // n offset
    int cc = (task & 7) * 8;   // k offset
    ushort8 r;
#pragma unroll
    for (int j = 0; j < 8; ++j) r[j] = t[rr * 65 + cc + j];
    *reinterpret_cast<ushort8*>(out + (size_t)(n0 + rr) * Kdim + k0 + cc) = r;
  }
}

// ---------------------------------------------------------------------------
// bf16 MFMA GEMM: C[M=4096][N] = A[M][768] * Bt[N][768]^T
// 128x128 block tile, BK=32, 4 waves, 4x4 16x16x32 frags per wave.
// global_load_lds staging (16B, linear LDS), double-buffered, ONE barrier
// per K-step (stage-after-read order; stage drains at next barrier).
// MODE 0: QKV epilogue (Q scaled, K/V fragment-linear scatter)
// MODE 1: proj epilogue (fp32 out + bias)
// ---------------------------------------------------------------------------
template <int MODE>
__global__ __launch_bounds__(256) void k_gemm(const unsigned short* __restrict__ A,
                                              const unsigned short* __restrict__ Bt,
                                              const float* __restrict__ bias,
                                              unsigned short* __restrict__ Qb,
                                              unsigned short* __restrict__ Kf,
                                              unsigned short* __restrict__ Vf,
                                              float* __restrict__ outf) {
  __shared__ unsigned short As[2][128 * 32];
  __shared__ unsigned short Bs[2][128 * 32];

  int tid = threadIdx.x;
  int lane = tid & 63, wave = tid >> 6;
  int wr = wave >> 1, wc = wave & 1;         // wave -> 64x64 subtile
  int m0 = blockIdx.y * 128, n0 = blockIdx.x * 128;
  int r16 = lane & 15, g = lane >> 4;

  // staging: 8 chunks of 1KB per tile (16 rows x 64B); wave stages 2 of A + 2 of B
  int ca0 = wave * 2, ca1 = wave * 2 + 1;
  int srow = lane >> 2, scol = (lane & 3) * 8;  // within-chunk source (row, col elems)

  f32x4 acc[4][4] = {};

#define GSTAGE(BUF, K0)                                                                 \
  do {                                                                                  \
    gload_lds16(A + (size_t)(m0 + ca0 * 16 + srow) * DMODEL + (K0) + scol,              \
                &As[BUF][ca0 * 512]);                                                   \
    gload_lds16(A + (size_t)(m0 + ca1 * 16 + srow) * DMODEL + (K0) + scol,              \
                &As[BUF][ca1 * 512]);                                                   \
    gload_lds16(Bt + (size_t)(n0 + ca0 * 16 + srow) * DMODEL + (K0) + scol,             \
                &Bs[BUF][ca0 * 512]);                                                   \
    gload_lds16(Bt + (size_t)(n0 + ca1 * 16 + srow) * DMODEL + (K0) + scol,             \
                &Bs[BUF][ca1 * 512]);                                                   \
  } while (0)

  GSTAGE(0, 0);
  for (int kt = 0; kt < DMODEL / 32; ++kt) {
    int cur = kt & 1;
    __syncthreads();  // drains prev stage (own vmcnt) + all waves' reads of buf[cur^1]

    bf16x8 af[4], bfr[4];
#pragma unroll
    for (int m = 0; m < 4; ++m)
      af[m] = *reinterpret_cast<const bf16x8*>(&As[cur][(wr * 64 + m * 16 + r16) * 32 + g * 8]);
#pragma unroll
    for (int n = 0; n < 4; ++n)
      bfr[n] = *reinterpret_cast<const bf16x8*>(&Bs[cur][(wc * 64 + n * 16 + r16) * 32 + g * 8]);

    if (kt < DMODEL / 32 - 1) GSTAGE(cur ^ 1, (kt + 1) * 32);

#pragma unroll
    for (int m = 0; m < 4; ++m)
#pragma unroll
      for (int n = 0; n < 4; ++n)
        acc[m][n] = __builtin_amdgcn_mfma_f32_16x16x32_bf16(af[m], bfr[n], acc[m][n], 0, 0, 0);
  }
#undef GSTAGE

  // Epilogue. C/D frag layout: col = lane&15, row = 4*(lane>>4) + reg  [HW-verified]
#pragma unroll
  for (int m = 0; m < 4; ++m) {
    int grow0 = m0 + wr * 64 + m * 16 + 4 * g;  // s index base (4 consecutive)
#pragma unroll
    for (int n = 0; n < 4; ++n) {
      int gcol = n0 + wc * 64 + n * 16 + r16;
      float bv = bias[gcol];
      if (MODE == 0) {
        int sect = gcol / DMODEL;        // uniform per block (768 = 6*128)
        int rem = gcol - sect * DMODEL;
        int h = rem >> 6, hd = rem & 63;
        if (sect == 2) {
          // V fragment-linear: elem (h,tile,f=j*2+kk,lane2=g2*16+r16v,e)
          //   = V[d = j*16+r16v][s = tile*64 + kk*32 + g2*8 + e]
          int j = hd >> 4, r16v = hd & 15;
          int tile = grow0 >> 6, kk = (grow0 >> 5) & 1, g2 = (grow0 >> 3) & 3, e0 = grow0 & 7;
          size_t base = (((size_t)h * 64 + tile) * 8 + (j * 2 + kk)) * 512 +
                        (size_t)(g2 * 16 + r16v) * 8 + e0;
          ushort4 pk;
          pk.x = f2bf(acc[m][n][0] + bv);
          pk.y = f2bf(acc[m][n][1] + bv);
          pk.z = f2bf(acc[m][n][2] + bv);
          pk.w = f2bf(acc[m][n][3] + bv);
          *reinterpret_cast<ushort4*>(Vf + base) = pk;
        } else if (sect == 0) {
          // Q: [h][s][d], folded 1/sqrt(64)*log2e (attention runs in exp2 domain)
#pragma unroll
          for (int i = 0; i < 4; ++i)
            Qb[((size_t)h * S_LEN + grow0 + i) * HDIM + hd] =
                f2bf((acc[m][n][i] + bv) * (0.125f * LOG2E));
        } else {
          // K fragment-linear: elem (h,tile,f=j*2+kk,lane2=g2*16+r16l,e)
          //   = K[s = tile*64 + krow][d = kk*32 + g2*8 + e]
          // krow = 32*(j&1) + 4*(j>>1) + 8*(r16l>>2) + (r16l&3)
          int kk = hd >> 5, g2 = (hd >> 3) & 3, e = hd & 7;
#pragma unroll
          for (int i = 0; i < 4; ++i) {
            int s = grow0 + i;
            int tile = s >> 6, r = s & 63;
            int j = (((r >> 2) & 1) << 1) | (r >> 5);
            int r16l = (r & 3) | (((r >> 3) & 3) << 2);
            size_t idx = (((size_t)h * 64 + tile) * 8 + (j * 2 + kk)) * 512 +
                         (size_t)(g2 * 16 + r16l) * 8 + e;
            Kf[idx] = f2bf(acc[m][n][i] + bv);
          }
        }
      } else {
#pragma unroll
        for (int i = 0; i < 4; ++i)
          outf[(size_t)(grow0 + i) * DMODEL + gcol] = acc[m][n][i] + bv;
      }
    }
  }
}

// ---------------------------------------------------------------------------
// Flash attention, BARRIER-FREE + LDS-FREE: direct fragment loads.
// K/V are fragment-linear in global memory, so each fragment is ONE fully
// coalesced 1KB wave-load with SGPR-base + constant-voffset addressing
// (zero per-tile VALU address math; tile advance is 2 SALU adds).
// Tile (16KB) fits L1, so the 4 waves' repeated reads mostly hit L1; K/V
// per head stays XCD-L2-resident via the block remap.
// Numerics identical to R7 (proven absmax 1.2e-3): peeled tile 0 max,
// defer-max THR=8, zinit C-seed, l via ones-MFMA, exp2 domain.
// K loads issued before V loads so V latency hides under QK^T + softmax.
// ---------------------------------------------------------------------------
__global__ __launch_bounds__(256, 3) void k_attn(const unsigned short* __restrict__ Q,
                                                 const unsigned short* __restrict__ Kf,
                                                 const unsigned short* __restrict__ Vf,
                                                 unsigned short* __restrict__ O) {
  int tid = threadIdx.x;
  int lane = tid & 63, wave = tid >> 6;
  int r16 = lane & 15, g = lane >> 4;

  // XCD-aware remap (bijective on 0..767)
  int bid = blockIdx.x;
  int gid = (bid & 7) * 96 + (bid >> 3);
  int h = gid >> 6;
  int qbase = (gid & 63) * 64 + wave * 16;

  const unsigned short* kb = Kf + (size_t)h * (64 * 4096);  // tile 0 base
  const unsigned short* vb = Vf + (size_t)h * (64 * 4096);
  int loff = lane * 8;  // loop-invariant lane offset (16B)

  // Q fragments (B-operand): lane holds Q[qbase+r16][8g..8g+7]
  const unsigned short* qptr = Q + ((size_t)h * S_LEN + qbase + r16) * HDIM + g * 8;
  bf16x8 qf0 = *reinterpret_cast<const bf16x8*>(qptr);
  bf16x8 qf1 = *reinterpret_cast<const bf16x8*>(qptr + 32);

  f32x4 oacc[4] = {};
  f32x4 lsum = {};            // C layout row=q=4g+i -> epilogue needs no shuffle
  f32x4 zinit = {};           // splat(-mrow); 0 for peeled tile 0
  float mrow = 0.f;           // running row max (exp2 domain), per-lane q=r16
  bf16x8 bones;
#pragma unroll
  for (int e = 0; e < 8; ++e) bones[e] = (__bf16)1.0f;

#define TILE_COMPUTE(KFR, VFR, FIRST)                                                   \
  do {                                                                                  \
    f32x4 s_[4];                                                                        \
    _Pragma("unroll") for (int j_ = 0; j_ < 4; ++j_) {                                  \
      f32x4 z_ = zinit;                                                                 \
      z_ = __builtin_amdgcn_mfma_f32_16x16x32_bf16(KFR[2 * j_], qf0, z_, 0, 0, 0);      \
      s_[j_] = __builtin_amdgcn_mfma_f32_16x16x32_bf16(KFR[2 * j_ + 1], qf1, z_, 0, 0, 0); \
    }                                                                                   \
    /* row max: max3-friendly triples (8 ops) + 2 shuffles */                           \
    float x1_ = fmaxf(fmaxf(s_[0][0], s_[0][1]), s_[0][2]);                             \
    float x2_ = fmaxf(fmaxf(s_[0][3], s_[1][0]), s_[1][1]);                             \
    float x3_ = fmaxf(fmaxf(s_[1][2], s_[1][3]), s_[2][0]);                             \
    float x4_ = fmaxf(fmaxf(s_[2][1], s_[2][2]), s_[2][3]);                             \
    float x5_ = fmaxf(fmaxf(s_[3][0], s_[3][1]), s_[3][2]);                             \
    float pm_ = fmaxf(fmaxf(fmaxf(x1_, x2_), fmaxf(x3_, x4_)), fmaxf(x5_, s_[3][3]));   \
    pm_ = fmaxf(pm_, __shfl_xor(pm_, 16));                                              \
    pm_ = fmaxf(pm_, __shfl_xor(pm_, 32));                                              \
    if (FIRST) {                                                                        \
      /* establish mrow exactly on tile 0 (p <= 1 afterwards) */                        \
      _Pragma("unroll") for (int j_ = 0; j_ < 4; ++j_)                                  \
        _Pragma("unroll") for (int i_ = 0; i_ < 4; ++i_) s_[j_][i_] -= pm_;             \
      mrow = pm_;                                                                       \
      zinit[0] = -mrow; zinit[1] = -mrow; zinit[2] = -mrow; zinit[3] = -mrow;           \
    } else if (__any(pm_ > 8.f)) { /* defer-max THR=8, wave-uniform, rare */            \
      float dl_ = fmaxf(pm_, 0.f);                                                      \
      float al_ = EXP2(-dl_);                                                           \
      float a0_ = __shfl(al_, 20 * g + 0), a1_ = __shfl(al_, 20 * g + 1);               \
      float a2_ = __shfl(al_, 20 * g + 2), a3_ = __shfl(al_, 20 * g + 3);               \
      lsum[0] *= a0_; lsum[1] *= a1_; lsum[2] *= a2_; lsum[3] *= a3_;                   \
      _Pragma("unroll") for (int j_ = 0; j_ < 4; ++j_) {                                \
        oacc[j_][0] *= a0_; oacc[j_][1] *= a1_;                                         \
        oacc[j_][2] *= a2_; oacc[j_][3] *= a3_;                                         \
      }                                                                                 \
      _Pragma("unroll") for (int j_ = 0; j_ < 4; ++j_)                                  \
        _Pragma("unroll") for (int i_ = 0; i_ < 4; ++i_) s_[j_][i_] -= dl_;             \
      mrow += dl_;                                                                      \
      zinit[0] = -mrow; zinit[1] = -mrow; zinit[2] = -mrow; zinit[3] = -mrow;           \
    }                                                                                   \
    float p_[4][4];                                                                     \
    _Pragma("unroll") for (int j_ = 0; j_ < 4; ++j_)                                    \
      _Pragma("unroll") for (int i_ = 0; i_ < 4; ++i_)                                  \
        p_[j_][i_] = EXP2(s_[j_][i_]);                                                  \
    /* lane-local P -> bf16 A-frags (v_cvt_pk_bf16_f32 pairs) */                        \
    bf16x8 pa0_, pa1_;                                                                  \
    _Pragma("unroll") for (int e_ = 0; e_ < 8; ++e_) {                                  \
      pa0_[e_] = (__bf16)p_[2 * (e_ >> 2)][e_ & 3];                                     \
      pa1_[e_] = (__bf16)p_[1 + 2 * (e_ >> 2)][e_ & 3];                                 \
    }                                                                                   \
    /* l from the SAME bf16 p-hat as PV (consistent denominator) */                     \
    lsum = __builtin_amdgcn_mfma_f32_16x16x32_bf16(pa0_, bones, lsum, 0, 0, 0);         \
    lsum = __builtin_amdgcn_mfma_f32_16x16x32_bf16(pa1_, bones, lsum, 0, 0, 0);         \
    _Pragma("unroll") for (int j_ = 0; j_ < 4; ++j_) {                                  \
      oacc[j_] = __builtin_amdgcn_mfma_f32_16x16x32_bf16(pa0_, VFR[2 * j_], oacc[j_], 0, 0, 0); \
      oacc[j_] = __builtin_amdgcn_mfma_f32_16x16x32_bf16(pa1_, VFR[2 * j_ + 1], oacc[j_], 0, 0, 0); \
    }                                                                                   \
  } while (0)

#define BODY(FIRSTF)                                                                    \
  do {                                                                                  \
    bf16x8 kfr_[8], vfr_[8];                                                            \
    _Pragma("unroll") for (int f_ = 0; f_ < 8; ++f_)                                    \
      kfr_[f_] = *reinterpret_cast<const bf16x8*>(kb + f_ * 512 + loff);                \
    _Pragma("unroll") for (int f_ = 0; f_ < 8; ++f_)                                    \
      vfr_[f_] = *reinterpret_cast<const bf16x8*>(vb + f_ * 512 + loff);                \
    TILE_COMPUTE(kfr_, vfr_, FIRSTF);                                                   \
    kb += 4096;                                                                         \
    vb += 4096;                                                                         \
  } while (0)

  BODY(true);  // peeled tile 0: establishes mrow exactly
#pragma unroll 2
  for (int t = 1; t < 64; ++t) {
    BODY(false);
  }
#undef BODY
#undef TILE_COMPUTE

  // ---- epilogue: O[s][h*64+d] bf16; lsum[i] is row q=4g+i's l (no shuffle)
#pragma unroll
  for (int i = 0; i < 4; ++i) {
    float linv = 1.0f / lsum[i];
    int srow = qbase + 4 * g + i;
#pragma unroll
    for (int j = 0; j < 4; ++j) {
      int col = h * HDIM + j * 16 + r16;
      O[(size_t)srow * DMODEL + col] = f2bf(oacc[j][i] * linv);
    }
  }
}

// ---------------------------------------------------------------------------
extern "C" void kernel_launch(void* const* d_in, const int* in_sizes, int n_in,
                              void* d_out, int out_size, void* d_ws, size_t ws_size,
                              hipStream_t stream) {
  const float* x = (const float*)d_in[0];       // [4096][768]
  const float* w_qkv = (const float*)d_in[1];   // [768][2304]
  const float* b_qkv = (const float*)d_in[2];   // [2304]
  const float* w_proj = (const float*)d_in[3];  // [768][768]
  const float* b_proj = (const float*)d_in[4];  // [768]
  float* out = (float*)d_out;                   // [4096][768]

  unsigned short* ws16 = (unsigned short*)d_ws;
  unsigned short* xb = ws16;                                   // 4096*768
  unsigned short* wqkvT = xb + (size_t)S_LEN * DMODEL;         // 2304*768
  unsigned short* wprojT = wqkvT + (size_t)DQKV * DMODEL;      // 768*768
  unsigned short* Qb = wprojT + (size_t)DMODEL * DMODEL;       // 12*4096*64
  unsigned short* Kf = Qb + (size_t)NHEAD * S_LEN * HDIM;
  unsigned short* Vf = Kf + (size_t)NHEAD * S_LEN * HDIM;
  unsigned short* Ob = xb;  // alias: x dead after QKV GEMM

  // 1) convert x
  k_convert<<<(S_LEN * DMODEL) / (256 * 8), 256, 0, stream>>>(x, xb, S_LEN * DMODEL);
  // 2) transpose-convert weights to [N][K] bf16
  k_transpose<<<dim3(DQKV / 64, DMODEL / 64), 256, 0, stream>>>(w_qkv, wqkvT, DMODEL, DQKV);
  k_transpose<<<dim3(DMODEL / 64, DMODEL / 64), 256, 0, stream>>>(w_proj, wprojT, DMODEL, DMODEL);
  // 3) QKV GEMM + fragment-linear scatter
  k_gemm<0><<<dim3(DQKV / 128, S_LEN / 128), 256, 0, stream>>>(xb, wqkvT, b_qkv, Qb, Kf, Vf, nullptr);
  // 4) attention (1D grid, XCD-remapped in-kernel; barrier-free, LDS-free)
  k_attn<<<768, 256, 0, stream>>>(Qb, Kf, Vf, Ob);
  // 5) output projection
  k_gemm<1><<<dim3(DMODEL / 128, S_LEN / 128), 256, 0, stream>>>(Ob, wprojT, b_proj, nullptr, nullptr, nullptr, out);
}

// Round 9
// 139.369 us; speedup vs baseline: 1.1424x; 1.1424x over previous
//
#include <hip/hip_runtime.h>

// Problem constants
#define S_LEN 4096
#define DMODEL 768
#define NHEAD 12
#define HDIM 64
#define DQKV 2304

typedef __attribute__((ext_vector_type(8))) __bf16 bf16x8;
typedef __attribute__((ext_vector_type(4))) float f32x4;
typedef __attribute__((ext_vector_type(8))) unsigned short ushort8;

#define LOG2E 1.4426950408889634f

#if __has_builtin(__builtin_amdgcn_exp2f)
#define EXP2(x) __builtin_amdgcn_exp2f(x)
#else
#define EXP2(x) exp2f(x)
#endif

static __device__ __forceinline__ unsigned short f2bf(float f) {
  unsigned int u = __float_as_uint(f);
  u += 0x7FFFu + ((u >> 16) & 1u);  // round-to-nearest-even
  return (unsigned short)(u >> 16);
}

// async global -> LDS, 16B per lane. Dest must be wave-uniform; HW writes
// lptr + lane*16. Global src is per-lane (contiguous here -> coalesced).
static __device__ __forceinline__ void gload_lds16(const unsigned short* g, unsigned short* l) {
  __builtin_amdgcn_global_load_lds(
      (const __attribute__((address_space(1))) unsigned int*)g,
      (__attribute__((address_space(3))) unsigned int*)l, 16, 0, 0);
}

// ---------------------------------------------------------------------------
// fp32 -> bf16 elementwise convert (n must be multiple of 8)
// ---------------------------------------------------------------------------
__global__ __launch_bounds__(256) void k_convert(const float* __restrict__ in,
                                                 unsigned short* __restrict__ out,
                                                 int n) {
  int i = (blockIdx.x * 256 + threadIdx.x) * 8;
  if (i >= n) return;
  const float4* p = reinterpret_cast<const float4*>(in + i);
  float4 a = p[0], b = p[1];
  ushort8 r;
  r[0] = f2bf(a.x); r[1] = f2bf(a.y); r[2] = f2bf(a.z); r[3] = f2bf(a.w);
  r[4] = f2bf(b.x); r[5] = f2bf(b.y); r[6] = f2bf(b.z); r[7] = f2bf(b.w);
  *reinterpret_cast<ushort8*>(out + i) = r;
}

// ---------------------------------------------------------------------------
// [K][N] fp32  ->  [N][K] bf16 transpose-convert, 64x64 tiles
// ---------------------------------------------------------------------------
__global__ __launch_bounds__(256) void k_transpose(const float* __restrict__ in,
                                                   unsigned short* __restrict__ out,
                                                   int Kdim, int Ndim) {
  __shared__ unsigned short t[64 * 65];
  int k0 = blockIdx.y * 64, n0 = blockIdx.x * 64;
  int tid = threadIdx.x;
#pragma unroll
  for (int p = 0; p < 4; ++p) {
    int r = p * 16 + (tid >> 4);   // k offset in tile
    int c = (tid & 15) * 4;        // n offset in tile
    float4 v = *reinterpret_cast<const float4*>(in + (size_t)(k0 + r) * Ndim + n0 + c);
    t[(c + 0) * 65 + r] = f2bf(v.x);
    t[(c + 1) * 65 + r] = f2bf(v.y);
    t[(c + 2) * 65 + r] = f2bf(v.z);
    t[(c + 3) * 65 + r] = f2bf(v.w);
  }
  __syncthreads();
#pragma unroll
  for (int p = 0; p < 2; ++p) {
    int task = p * 256 + tid;
    int rr = task >> 3;        // n offset
    int cc = (task & 7) * 8;   // k offset
    ushort8 r;
#pragma unroll
    for (int j = 0; j < 8; ++j) r[j] = t[rr * 65 + cc + j];
    *reinterpret_cast<ushort8*>(out + (size_t)(n0 + rr) * Kdim + k0 + cc) = r;
  }
}

// ---------------------------------------------------------------------------
// bf16 MFMA GEMM: C[M=4096][N] = A[M][768] * Bt[N][768]^T
// 128x128 block tile, BK=32, 4 waves, 4x4 16x16x32 frags per wave.
// global_load_lds staging (16B, linear LDS), double-buffered, ONE barrier
// per K-step (stage-after-read order; stage drains at next barrier).
// MODE 0: QKV epilogue (Q scaled, K/V fragment-linear scatter)
// MODE 1: proj epilogue (fp32 out + bias)
// ---------------------------------------------------------------------------
template <int MODE>
__global__ __launch_bounds__(256) void k_gemm(const unsigned short* __restrict__ A,
                                              const unsigned short* __restrict__ Bt,
                                              const float* __restrict__ bias,
                                              unsigned short* __restrict__ Qb,
                                              unsigned short* __restrict__ Kf,
                                              unsigned short* __restrict__ Vf,
                                              float* __restrict__ outf) {
  __shared__ unsigned short As[2][128 * 32];
  __shared__ unsigned short Bs[2][128 * 32];

  int tid = threadIdx.x;
  int lane = tid & 63, wave = tid >> 6;
  int wr = wave >> 1, wc = wave & 1;         // wave -> 64x64 subtile
  int m0 = blockIdx.y * 128, n0 = blockIdx.x * 128;
  int r16 = lane & 15, g = lane >> 4;

  // staging: 8 chunks of 1KB per tile (16 rows x 64B); wave stages 2 of A + 2 of B
  int ca0 = wave * 2, ca1 = wave * 2 + 1;
  int srow = lane >> 2, scol = (lane & 3) * 8;  // within-chunk source (row, col elems)

  f32x4 acc[4][4] = {};

#define GSTAGE(BUF, K0)                                                                 \
  do {                                                                                  \
    gload_lds16(A + (size_t)(m0 + ca0 * 16 + srow) * DMODEL + (K0) + scol,              \
                &As[BUF][ca0 * 512]);                                                   \
    gload_lds16(A + (size_t)(m0 + ca1 * 16 + srow) * DMODEL + (K0) + scol,              \
                &As[BUF][ca1 * 512]);                                                   \
    gload_lds16(Bt + (size_t)(n0 + ca0 * 16 + srow) * DMODEL + (K0) + scol,             \
                &Bs[BUF][ca0 * 512]);                                                   \
    gload_lds16(Bt + (size_t)(n0 + ca1 * 16 + srow) * DMODEL + (K0) + scol,             \
                &Bs[BUF][ca1 * 512]);                                                   \
  } while (0)

  GSTAGE(0, 0);
  for (int kt = 0; kt < DMODEL / 32; ++kt) {
    int cur = kt & 1;
    __syncthreads();  // drains prev stage (own vmcnt) + all waves' reads of buf[cur^1]

    bf16x8 af[4], bfr[4];
#pragma unroll
    for (int m = 0; m < 4; ++m)
      af[m] = *reinterpret_cast<const bf16x8*>(&As[cur][(wr * 64 + m * 16 + r16) * 32 + g * 8]);
#pragma unroll
    for (int n = 0; n < 4; ++n)
      bfr[n] = *reinterpret_cast<const bf16x8*>(&Bs[cur][(wc * 64 + n * 16 + r16) * 32 + g * 8]);

    if (kt < DMODEL / 32 - 1) GSTAGE(cur ^ 1, (kt + 1) * 32);

#pragma unroll
    for (int m = 0; m < 4; ++m)
#pragma unroll
      for (int n = 0; n < 4; ++n)
        acc[m][n] = __builtin_amdgcn_mfma_f32_16x16x32_bf16(af[m], bfr[n], acc[m][n], 0, 0, 0);
  }
#undef GSTAGE

  // Epilogue. C/D frag layout: col = lane&15, row = 4*(lane>>4) + reg  [HW-verified]
#pragma unroll
  for (int m = 0; m < 4; ++m) {
    int grow0 = m0 + wr * 64 + m * 16 + 4 * g;  // s index base (4 consecutive)
#pragma unroll
    for (int n = 0; n < 4; ++n) {
      int gcol = n0 + wc * 64 + n * 16 + r16;
      float bv = bias[gcol];
      if (MODE == 0) {
        int sect = gcol / DMODEL;        // uniform per block (768 = 6*128)
        int rem = gcol - sect * DMODEL;
        int h = rem >> 6, hd = rem & 63;
        if (sect == 2) {
          // V fragment-linear: elem (h,tile,f=j*2+kk,lane2=g2*16+r16v,e)
          //   = V[d = j*16+r16v][s = tile*64 + kk*32 + g2*8 + e]
          int j = hd >> 4, r16v = hd & 15;
          int tile = grow0 >> 6, kk = (grow0 >> 5) & 1, g2 = (grow0 >> 3) & 3, e0 = grow0 & 7;
          size_t base = (((size_t)h * 64 + tile) * 8 + (j * 2 + kk)) * 512 +
                        (size_t)(g2 * 16 + r16v) * 8 + e0;
          ushort4 pk;
          pk.x = f2bf(acc[m][n][0] + bv);
          pk.y = f2bf(acc[m][n][1] + bv);
          pk.z = f2bf(acc[m][n][2] + bv);
          pk.w = f2bf(acc[m][n][3] + bv);
          *reinterpret_cast<ushort4*>(Vf + base) = pk;
        } else if (sect == 0) {
          // Q: [h][s][d], folded 1/sqrt(64)*log2e (attention runs in exp2 domain)
#pragma unroll
          for (int i = 0; i < 4; ++i)
            Qb[((size_t)h * S_LEN + grow0 + i) * HDIM + hd] =
                f2bf((acc[m][n][i] + bv) * (0.125f * LOG2E));
        } else {
          // K fragment-linear: elem (h,tile,f=j*2+kk,lane2=g2*16+r16l,e)
          //   = K[s = tile*64 + krow][d = kk*32 + g2*8 + e]
          // krow = 32*(j&1) + 4*(j>>1) + 8*(r16l>>2) + (r16l&3)
          int kk = hd >> 5, g2 = (hd >> 3) & 3, e = hd & 7;
#pragma unroll
          for (int i = 0; i < 4; ++i) {
            int s = grow0 + i;
            int tile = s >> 6, r = s & 63;
            int j = (((r >> 2) & 1) << 1) | (r >> 5);
            int r16l = (r & 3) | (((r >> 3) & 3) << 2);
            size_t idx = (((size_t)h * 64 + tile) * 8 + (j * 2 + kk)) * 512 +
                         (size_t)(g2 * 16 + r16l) * 8 + e;
            Kf[idx] = f2bf(acc[m][n][i] + bv);
          }
        }
      } else {
#pragma unroll
        for (int i = 0; i < 4; ++i)
          outf[(size_t)(grow0 + i) * DMODEL + gcol] = acc[m][n][i] + bv;
      }
    }
  }
}

// ---------------------------------------------------------------------------
// Flash attention, LDS-staged fragment-linear K/V, 32 q-rows PER WAVE.
// R7's limiter was the LDS pipe: all waves redundantly read the same 16KB
// of K/V frags. Now 2 waves/block, each handling TWO 16-row q-sets ->
// same fragment reads serve 2x the work (LDS traffic per q halved).
// Order QK(A),QK(B),softmax(A),PV(A),softmax(B),PV(B): B's reg-resident
// MFMAs overlap A's softmax VALU. Numerics = proven R7 path per q-set.
// Grid stays 768 (balanced, 3 blocks/CU, 6 waves/CU).
// ---------------------------------------------------------------------------
__global__ __launch_bounds__(128, 2) void k_attn(const unsigned short* __restrict__ Q,
                                                 const unsigned short* __restrict__ Kf,
                                                 const unsigned short* __restrict__ Vf,
                                                 unsigned short* __restrict__ O) {
  __shared__ unsigned short ldsK[2][4096];
  __shared__ unsigned short ldsV[2][4096];

  int tid = threadIdx.x;
  int lane = tid & 63, wave = tid >> 6;  // wave in {0,1}
  int r16 = lane & 15, g = lane >> 4;

  // XCD-aware remap (bijective on 0..767)
  int bid = blockIdx.x;
  int gid = (bid & 7) * 96 + (bid >> 3);
  int h = gid >> 6;
  int qbaseA = (gid & 63) * 64 + wave * 16;  // q-set A rows
  int qbaseB = qbaseA + 32;                  // q-set B rows

  const unsigned short* KfH = Kf + (size_t)h * (64 * 4096);
  const unsigned short* VfH = Vf + (size_t)h * (64 * 4096);

  // Q fragments for both sets (B-operand): lane holds Q[qbase+r16][8g..8g+7]
  const unsigned short* qpA = Q + ((size_t)h * S_LEN + qbaseA + r16) * HDIM + g * 8;
  const unsigned short* qpB = Q + ((size_t)h * S_LEN + qbaseB + r16) * HDIM + g * 8;
  bf16x8 qf0a = *reinterpret_cast<const bf16x8*>(qpA);
  bf16x8 qf1a = *reinterpret_cast<const bf16x8*>(qpA + 32);
  bf16x8 qf0b = *reinterpret_cast<const bf16x8*>(qpB);
  bf16x8 qf1b = *reinterpret_cast<const bf16x8*>(qpB + 32);

  f32x4 oaccA[4] = {}, oaccB[4] = {};
  f32x4 lsumA = {}, lsumB = {};
  f32x4 zinitA = {}, zinitB = {};
  float mrowA = 0.f, mrowB = 0.f;
  bf16x8 bones;
#pragma unroll
  for (int e = 0; e < 8; ++e) bones[e] = (__bf16)1.0f;

  // this wave's four 1KB chunks per buffer (2 waves x 4 chunks = 8)
  int c0 = wave * 4, c1 = c0 + 1, c2 = c0 + 2, c3 = c0 + 3;

#define STAGE(BUF, T)                                                        \
  do {                                                                       \
    const unsigned short* kg_ = KfH + (size_t)(T) * 4096;                    \
    const unsigned short* vg_ = VfH + (size_t)(T) * 4096;                    \
    gload_lds16(kg_ + c0 * 512 + lane * 8, &ldsK[BUF][c0 * 512]);            \
    gload_lds16(kg_ + c1 * 512 + lane * 8, &ldsK[BUF][c1 * 512]);            \
    gload_lds16(kg_ + c2 * 512 + lane * 8, &ldsK[BUF][c2 * 512]);            \
    gload_lds16(kg_ + c3 * 512 + lane * 8, &ldsK[BUF][c3 * 512]);            \
    gload_lds16(vg_ + c0 * 512 + lane * 8, &ldsV[BUF][c0 * 512]);            \
    gload_lds16(vg_ + c1 * 512 + lane * 8, &ldsV[BUF][c1 * 512]);            \
    gload_lds16(vg_ + c2 * 512 + lane * 8, &ldsV[BUF][c2 * 512]);            \
    gload_lds16(vg_ + c3 * 512 + lane * 8, &ldsV[BUF][c3 * 512]);            \
  } while (0)

// QK^T for one q-set: s[j] = K_frags x Qset + zinit (exp2 domain)
#define QK(SARR, QF0, QF1, ZI)                                                          \
  do {                                                                                  \
    _Pragma("unroll") for (int j_ = 0; j_ < 4; ++j_) {                                  \
      f32x4 z_ = ZI;                                                                    \
      z_ = __builtin_amdgcn_mfma_f32_16x16x32_bf16(kfr_[2 * j_], QF0, z_, 0, 0, 0);     \
      SARR[j_] = __builtin_amdgcn_mfma_f32_16x16x32_bf16(kfr_[2 * j_ + 1], QF1, z_, 0, 0, 0); \
    }                                                                                   \
  } while (0)

// softmax + PV for one q-set (defer-max THR=8; peeled FIRST establishes max)
#define SOFTPV(SARR, MROW, ZI, LSUM, OACC, FIRST)                                       \
  do {                                                                                  \
    float x1_ = fmaxf(fmaxf(SARR[0][0], SARR[0][1]), SARR[0][2]);                       \
    float x2_ = fmaxf(fmaxf(SARR[0][3], SARR[1][0]), SARR[1][1]);                       \
    float x3_ = fmaxf(fmaxf(SARR[1][2], SARR[1][3]), SARR[2][0]);                       \
    float x4_ = fmaxf(fmaxf(SARR[2][1], SARR[2][2]), SARR[2][3]);                       \
    float x5_ = fmaxf(fmaxf(SARR[3][0], SARR[3][1]), SARR[3][2]);                       \
    float pm_ = fmaxf(fmaxf(fmaxf(x1_, x2_), fmaxf(x3_, x4_)), fmaxf(x5_, SARR[3][3])); \
    pm_ = fmaxf(pm_, __shfl_xor(pm_, 16));                                              \
    pm_ = fmaxf(pm_, __shfl_xor(pm_, 32));                                              \
    if (FIRST) {                                                                        \
      _Pragma("unroll") for (int j_ = 0; j_ < 4; ++j_)                                  \
        _Pragma("unroll") for (int i_ = 0; i_ < 4; ++i_) SARR[j_][i_] -= pm_;           \
      MROW = pm_;                                                                       \
      ZI[0] = -MROW; ZI[1] = -MROW; ZI[2] = -MROW; ZI[3] = -MROW;                       \
    } else if (__any(pm_ > 8.f)) {                                                      \
      float dl_ = fmaxf(pm_, 0.f);                                                      \
      float al_ = EXP2(-dl_);                                                           \
      float a0_ = __shfl(al_, 20 * g + 0), a1_ = __shfl(al_, 20 * g + 1);               \
      float a2_ = __shfl(al_, 20 * g + 2), a3_ = __shfl(al_, 20 * g + 3);               \
      LSUM[0] *= a0_; LSUM[1] *= a1_; LSUM[2] *= a2_; LSUM[3] *= a3_;                   \
      _Pragma("unroll") for (int j_ = 0; j_ < 4; ++j_) {                                \
        OACC[j_][0] *= a0_; OACC[j_][1] *= a1_;                                         \
        OACC[j_][2] *= a2_; OACC[j_][3] *= a3_;                                         \
      }                                                                                 \
      _Pragma("unroll") for (int j_ = 0; j_ < 4; ++j_)                                  \
        _Pragma("unroll") for (int i_ = 0; i_ < 4; ++i_) SARR[j_][i_] -= dl_;           \
      MROW += dl_;                                                                      \
      ZI[0] = -MROW; ZI[1] = -MROW; ZI[2] = -MROW; ZI[3] = -MROW;                       \
    }                                                                                   \
    float p_[4][4];                                                                     \
    _Pragma("unroll") for (int j_ = 0; j_ < 4; ++j_)                                    \
      _Pragma("unroll") for (int i_ = 0; i_ < 4; ++i_)                                  \
        p_[j_][i_] = EXP2(SARR[j_][i_]);                                                \
    bf16x8 pa0_, pa1_;                                                                  \
    _Pragma("unroll") for (int e_ = 0; e_ < 8; ++e_) {                                  \
      pa0_[e_] = (__bf16)p_[2 * (e_ >> 2)][e_ & 3];                                     \
      pa1_[e_] = (__bf16)p_[1 + 2 * (e_ >> 2)][e_ & 3];                                 \
    }                                                                                   \
    LSUM = __builtin_amdgcn_mfma_f32_16x16x32_bf16(pa0_, bones, LSUM, 0, 0, 0);         \
    LSUM = __builtin_amdgcn_mfma_f32_16x16x32_bf16(pa1_, bones, LSUM, 0, 0, 0);         \
    _Pragma("unroll") for (int j_ = 0; j_ < 4; ++j_) {                                  \
      OACC[j_] = __builtin_amdgcn_mfma_f32_16x16x32_bf16(pa0_, vfr_[2 * j_], OACC[j_], 0, 0, 0); \
      OACC[j_] = __builtin_amdgcn_mfma_f32_16x16x32_bf16(pa1_, vfr_[2 * j_ + 1], OACC[j_], 0, 0, 0); \
    }                                                                                   \
  } while (0)

#define BODY(CUR, DO_STAGE, T, FIRSTF)                                                  \
  do {                                                                                  \
    __syncthreads(); /* buf[CUR] staged (own vmcnt drained); prev reads done */         \
    bf16x8 kfr_[8], vfr_[8];                                                            \
    _Pragma("unroll") for (int f_ = 0; f_ < 8; ++f_) {                                  \
      kfr_[f_] = *reinterpret_cast<const bf16x8*>(&ldsK[CUR][f_ * 512 + lane * 8]);     \
      vfr_[f_] = *reinterpret_cast<const bf16x8*>(&ldsV[CUR][f_ * 512 + lane * 8]);     \
    }                                                                                   \
    if (DO_STAGE) STAGE((CUR) ^ 1, (T) + 1);                                            \
    f32x4 sA_[4], sB_[4];                                                               \
    QK(sA_, qf0a, qf1a, zinitA);                                                        \
    QK(sB_, qf0b, qf1b, zinitB);                                                        \
    SOFTPV(sA_, mrowA, zinitA, lsumA, oaccA, FIRSTF);                                   \
    SOFTPV(sB_, mrowB, zinitB, lsumB, oaccB, FIRSTF);                                   \
  } while (0)

  STAGE(0, 0);
  BODY(0, true, 0, true);  // peeled tile 0: establishes mrow exactly
  for (int pr = 0; pr < 31; ++pr) {
    BODY(1, true, 2 * pr + 1, false);
    BODY(0, true, 2 * pr + 2, false);
  }
  BODY(1, false, 63, false);
#undef BODY
#undef SOFTPV
#undef QK
#undef STAGE

  // ---- epilogue: O[s][h*64+d] bf16; lsum[i] is row q=4g+i's l (no shuffle)
#pragma unroll
  for (int i = 0; i < 4; ++i) {
    float linvA = 1.0f / lsumA[i];
    float linvB = 1.0f / lsumB[i];
    int srowA = qbaseA + 4 * g + i;
    int srowB = qbaseB + 4 * g + i;
#pragma unroll
    for (int j = 0; j < 4; ++j) {
      int col = h * HDIM + j * 16 + r16;
      O[(size_t)srowA * DMODEL + col] = f2bf(oaccA[j][i] * linvA);
      O[(size_t)srowB * DMODEL + col] = f2bf(oaccB[j][i] * linvB);
    }
  }
}

// ---------------------------------------------------------------------------
extern "C" void kernel_launch(void* const* d_in, const int* in_sizes, int n_in,
                              void* d_out, int out_size, void* d_ws, size_t ws_size,
                              hipStream_t stream) {
  const float* x = (const float*)d_in[0];       // [4096][768]
  const float* w_qkv = (const float*)d_in[1];   // [768][2304]
  const float* b_qkv = (const float*)d_in[2];   // [2304]
  const float* w_proj = (const float*)d_in[3];  // [768][768]
  const float* b_proj = (const float*)d_in[4];  // [768]
  float* out = (float*)d_out;                   // [4096][768]

  unsigned short* ws16 = (unsigned short*)d_ws;
  unsigned short* xb = ws16;                                   // 4096*768
  unsigned short* wqkvT = xb + (size_t)S_LEN * DMODEL;         // 2304*768
  unsigned short* wprojT = wqkvT + (size_t)DQKV * DMODEL;      // 768*768
  unsigned short* Qb = wprojT + (size_t)DMODEL * DMODEL;       // 12*4096*64
  unsigned short* Kf = Qb + (size_t)NHEAD * S_LEN * HDIM;
  unsigned short* Vf = Kf + (size_t)NHEAD * S_LEN * HDIM;
  unsigned short* Ob = xb;  // alias: x dead after QKV GEMM

  // 1) convert x
  k_convert<<<(S_LEN * DMODEL) / (256 * 8), 256, 0, stream>>>(x, xb, S_LEN * DMODEL);
  // 2) transpose-convert weights to [N][K] bf16
  k_transpose<<<dim3(DQKV / 64, DMODEL / 64), 256, 0, stream>>>(w_qkv, wqkvT, DMODEL, DQKV);
  k_transpose<<<dim3(DMODEL / 64, DMODEL / 64), 256, 0, stream>>>(w_proj, wprojT, DMODEL, DMODEL);
  // 3) QKV GEMM + fragment-linear scatter
  k_gemm<0><<<dim3(DQKV / 128, S_LEN / 128), 256, 0, stream>>>(xb, wqkvT, b_qkv, Qb, Kf, Vf, nullptr);
  // 4) attention (1D grid, XCD-remapped in-kernel; 2 waves x 32 q-rows)
  k_attn<<<768, 128, 0, stream>>>(Qb, Kf, Vf, Ob);
  // 5) output projection
  k_gemm<1><<<dim3(DMODEL / 128, S_LEN / 128), 256, 0, stream>>>(Ob, wprojT, b_proj, nullptr, nullptr, nullptr, out);
}

// Round 10
// 131.210 us; speedup vs baseline: 1.2134x; 1.0622x over previous
//
#include <hip/hip_runtime.h>

// Problem constants
#define S_LEN 4096
#define DMODEL 768
#define NHEAD 12
#define HDIM 64
#define DQKV 2304

typedef __attribute__((ext_vector_type(8))) __bf16 bf16x8;
typedef __attribute__((ext_vector_type(4))) float f32x4;
typedef __attribute__((ext_vector_type(8))) unsigned short ushort8;

#define LOG2E 1.4426950408889634f

#if __has_builtin(__builtin_amdgcn_exp2f)
#define EXP2(x) __builtin_amdgcn_exp2f(x)
#else
#define EXP2(x) exp2f(x)
#endif

static __device__ __forceinline__ unsigned short f2bf(float f) {
  unsigned int u = __float_as_uint(f);
  u += 0x7FFFu + ((u >> 16) & 1u);  // round-to-nearest-even
  return (unsigned short)(u >> 16);
}

// async global -> LDS, 16B per lane. Dest must be wave-uniform; HW writes
// lptr + lane*16. Global src is per-lane (contiguous here -> coalesced).
static __device__ __forceinline__ void gload_lds16(const unsigned short* g, unsigned short* l) {
  __builtin_amdgcn_global_load_lds(
      (const __attribute__((address_space(1))) unsigned int*)g,
      (__attribute__((address_space(3))) unsigned int*)l, 16, 0, 0);
}

// ---------------------------------------------------------------------------
// fp32 -> bf16 elementwise convert (n must be multiple of 8)
// ---------------------------------------------------------------------------
__global__ __launch_bounds__(256) void k_convert(const float* __restrict__ in,
                                                 unsigned short* __restrict__ out,
                                                 int n) {
  int i = (blockIdx.x * 256 + threadIdx.x) * 8;
  if (i >= n) return;
  const float4* p = reinterpret_cast<const float4*>(in + i);
  float4 a = p[0], b = p[1];
  ushort8 r;
  r[0] = f2bf(a.x); r[1] = f2bf(a.y); r[2] = f2bf(a.z); r[3] = f2bf(a.w);
  r[4] = f2bf(b.x); r[5] = f2bf(b.y); r[6] = f2bf(b.z); r[7] = f2bf(b.w);
  *reinterpret_cast<ushort8*>(out + i) = r;
}

// ---------------------------------------------------------------------------
// [K][N] fp32  ->  [N][K] bf16 transpose-convert, 64x64 tiles
// ---------------------------------------------------------------------------
__global__ __launch_bounds__(256) void k_transpose(const float* __restrict__ in,
                                                   unsigned short* __restrict__ out,
                                                   int Kdim, int Ndim) {
  __shared__ unsigned short t[64 * 65];
  int k0 = blockIdx.y * 64, n0 = blockIdx.x * 64;
  int tid = threadIdx.x;
#pragma unroll
  for (int p = 0; p < 4; ++p) {
    int r = p * 16 + (tid >> 4);   // k offset in tile
    int c = (tid & 15) * 4;        // n offset in tile
    float4 v = *reinterpret_cast<const float4*>(in + (size_t)(k0 + r) * Ndim + n0 + c);
    t[(c + 0) * 65 + r] = f2bf(v.x);
    t[(c + 1) * 65 + r] = f2bf(v.y);
    t[(c + 2) * 65 + r] = f2bf(v.z);
    t[(c + 3) * 65 + r] = f2bf(v.w);
  }
  __syncthreads();
#pragma unroll
  for (int p = 0; p < 2; ++p) {
    int task = p * 256 + tid;
    int rr = task >> 3;        // n offset
    int cc = (task & 7) * 8;   // k offset
    ushort8 r;
#pragma unroll
    for (int j = 0; j < 8; ++j) r[j] = t[rr * 65 + cc + j];
    *reinterpret_cast<ushort8*>(out + (size_t)(n0 + rr) * Kdim + k0 + cc) = r;
  }
}

// ---------------------------------------------------------------------------
// bf16 MFMA GEMM: C[M=4096][N] = A[M][768] * Bt[N][768]^T
// 128x128 block tile, BK=32, 4 waves, 4x4 16x16x32 frags per wave.
// global_load_lds staging (16B, linear LDS), double-buffered, ONE barrier
// per K-step (stage-after-read order; stage drains at next barrier).
// MODE 0: QKV epilogue (Q scaled, K/V fragment-linear scatter)
// MODE 1: proj epilogue (fp32 out + bias)
// ---------------------------------------------------------------------------
template <int MODE>
__global__ __launch_bounds__(256) void k_gemm(const unsigned short* __restrict__ A,
                                              const unsigned short* __restrict__ Bt,
                                              const float* __restrict__ bias,
                                              unsigned short* __restrict__ Qb,
                                              unsigned short* __restrict__ Kf,
                                              unsigned short* __restrict__ Vf,
                                              float* __restrict__ outf) {
  __shared__ unsigned short As[2][128 * 32];
  __shared__ unsigned short Bs[2][128 * 32];

  int tid = threadIdx.x;
  int lane = tid & 63, wave = tid >> 6;
  int wr = wave >> 1, wc = wave & 1;         // wave -> 64x64 subtile
  int m0 = blockIdx.y * 128, n0 = blockIdx.x * 128;
  int r16 = lane & 15, g = lane >> 4;

  // staging: 8 chunks of 1KB per tile (16 rows x 64B); wave stages 2 of A + 2 of B
  int ca0 = wave * 2, ca1 = wave * 2 + 1;
  int srow = lane >> 2, scol = (lane & 3) * 8;  // within-chunk source (row, col elems)

  f32x4 acc[4][4] = {};

#define GSTAGE(BUF, K0)                                                                 \
  do {                                                                                  \
    gload_lds16(A + (size_t)(m0 + ca0 * 16 + srow) * DMODEL + (K0) + scol,              \
                &As[BUF][ca0 * 512]);                                                   \
    gload_lds16(A + (size_t)(m0 + ca1 * 16 + srow) * DMODEL + (K0) + scol,              \
                &As[BUF][ca1 * 512]);                                                   \
    gload_lds16(Bt + (size_t)(n0 + ca0 * 16 + srow) * DMODEL + (K0) + scol,             \
                &Bs[BUF][ca0 * 512]);                                                   \
    gload_lds16(Bt + (size_t)(n0 + ca1 * 16 + srow) * DMODEL + (K0) + scol,             \
                &Bs[BUF][ca1 * 512]);                                                   \
  } while (0)

  GSTAGE(0, 0);
  for (int kt = 0; kt < DMODEL / 32; ++kt) {
    int cur = kt & 1;
    __syncthreads();  // drains prev stage (own vmcnt) + all waves' reads of buf[cur^1]

    bf16x8 af[4], bfr[4];
#pragma unroll
    for (int m = 0; m < 4; ++m)
      af[m] = *reinterpret_cast<const bf16x8*>(&As[cur][(wr * 64 + m * 16 + r16) * 32 + g * 8]);
#pragma unroll
    for (int n = 0; n < 4; ++n)
      bfr[n] = *reinterpret_cast<const bf16x8*>(&Bs[cur][(wc * 64 + n * 16 + r16) * 32 + g * 8]);

    if (kt < DMODEL / 32 - 1) GSTAGE(cur ^ 1, (kt + 1) * 32);

#pragma unroll
    for (int m = 0; m < 4; ++m)
#pragma unroll
      for (int n = 0; n < 4; ++n)
        acc[m][n] = __builtin_amdgcn_mfma_f32_16x16x32_bf16(af[m], bfr[n], acc[m][n], 0, 0, 0);
  }
#undef GSTAGE

  // Epilogue. C/D frag layout: col = lane&15, row = 4*(lane>>4) + reg  [HW-verified]
#pragma unroll
  for (int m = 0; m < 4; ++m) {
    int grow0 = m0 + wr * 64 + m * 16 + 4 * g;  // s index base (4 consecutive)
#pragma unroll
    for (int n = 0; n < 4; ++n) {
      int gcol = n0 + wc * 64 + n * 16 + r16;
      float bv = bias[gcol];
      if (MODE == 0) {
        int sect = gcol / DMODEL;        // uniform per block (768 = 6*128)
        int rem = gcol - sect * DMODEL;
        int h = rem >> 6, hd = rem & 63;
        if (sect == 2) {
          // V fragment-linear: elem (h,tile,f=j*2+kk,lane2=g2*16+r16v,e)
          //   = V[d = j*16+r16v][s = tile*64 + kk*32 + g2*8 + e]
          int j = hd >> 4, r16v = hd & 15;
          int tile = grow0 >> 6, kk = (grow0 >> 5) & 1, g2 = (grow0 >> 3) & 3, e0 = grow0 & 7;
          size_t base = (((size_t)h * 64 + tile) * 8 + (j * 2 + kk)) * 512 +
                        (size_t)(g2 * 16 + r16v) * 8 + e0;
          ushort4 pk;
          pk.x = f2bf(acc[m][n][0] + bv);
          pk.y = f2bf(acc[m][n][1] + bv);
          pk.z = f2bf(acc[m][n][2] + bv);
          pk.w = f2bf(acc[m][n][3] + bv);
          *reinterpret_cast<ushort4*>(Vf + base) = pk;
        } else if (sect == 0) {
          // Q: [h][s][d], folded 1/sqrt(64)*log2e (attention runs in exp2 domain)
#pragma unroll
          for (int i = 0; i < 4; ++i)
            Qb[((size_t)h * S_LEN + grow0 + i) * HDIM + hd] =
                f2bf((acc[m][n][i] + bv) * (0.125f * LOG2E));
        } else {
          // K fragment-linear: elem (h,tile,f=j*2+kk,lane2=g2*16+r16l,e)
          //   = K[s = tile*64 + krow][d = kk*32 + g2*8 + e]
          // krow = 32*(j&1) + 4*(j>>1) + 8*(r16l>>2) + (r16l&3)
          int kk = hd >> 5, g2 = (hd >> 3) & 3, e = hd & 7;
#pragma unroll
          for (int i = 0; i < 4; ++i) {
            int s = grow0 + i;
            int tile = s >> 6, r = s & 63;
            int j = (((r >> 2) & 1) << 1) | (r >> 5);
            int r16l = (r & 3) | (((r >> 3) & 3) << 2);
            size_t idx = (((size_t)h * 64 + tile) * 8 + (j * 2 + kk)) * 512 +
                         (size_t)(g2 * 16 + r16l) * 8 + e;
            Kf[idx] = f2bf(acc[m][n][i] + bv);
          }
        }
      } else {
#pragma unroll
        for (int i = 0; i < 4; ++i)
          outf[(size_t)(grow0 + i) * DMODEL + gcol] = acc[m][n][i] + bv;
      }
    }
  }
}

// ---------------------------------------------------------------------------
// Flash attention, KV-SPLIT x2: grid 768 = 12 heads x 32 q-blocks(128 rows)
// x 2 KV-halves. 4 waves/block x 32 q-rows (two 16-row sets A/B) -> keeps
// R9's 2x LDS amortization AND R7's 12 waves/CU TLP. Each block handles 32
// KV tiles and writes fp32 UNNORMALIZED partials (O', l, m); k_combine
// merges the two halves. Numerics per half = proven R7 path (peeled tile-0,
// defer-max THR=8, zinit C-seed, ones-MFMA l, exp2 domain).
// ---------------------------------------------------------------------------
__global__ __launch_bounds__(256, 3) void k_attn(const unsigned short* __restrict__ Q,
                                                 const unsigned short* __restrict__ Kf,
                                                 const unsigned short* __restrict__ Vf,
                                                 float* __restrict__ Opart,
                                                 float* __restrict__ Lpart,
                                                 float* __restrict__ Mpart) {
  __shared__ unsigned short ldsK[2][4096];
  __shared__ unsigned short ldsV[2][4096];

  int tid = threadIdx.x;
  int lane = tid & 63, wave = tid >> 6;  // wave in 0..3
  int r16 = lane & 15, g = lane >> 4;

  // XCD-aware remap (bijective on 0..767)
  int bid = blockIdx.x;
  int gid = (bid & 7) * 96 + (bid >> 3);
  int h = gid >> 6;            // head
  int rem = gid & 63;
  int half = rem & 1;          // KV half
  int qb = rem >> 1;           // q-block (128 rows)
  int qbaseA = qb * 128 + wave * 16;
  int qbaseB = qbaseA + 64;
  int tb = half * 32;          // first tile of this half

  const unsigned short* KfH = Kf + (size_t)h * (64 * 4096);
  const unsigned short* VfH = Vf + (size_t)h * (64 * 4096);
  float* OpH = Opart + ((size_t)half * NHEAD + h) * S_LEN * HDIM;
  float* LpH = Lpart + ((size_t)half * NHEAD + h) * S_LEN;
  float* MpH = Mpart + ((size_t)half * NHEAD + h) * S_LEN;

  // Q fragments for both sets (B-operand): lane holds Q[qbase+r16][8g..8g+7]
  const unsigned short* qpA = Q + ((size_t)h * S_LEN + qbaseA + r16) * HDIM + g * 8;
  const unsigned short* qpB = Q + ((size_t)h * S_LEN + qbaseB + r16) * HDIM + g * 8;
  bf16x8 qf0a = *reinterpret_cast<const bf16x8*>(qpA);
  bf16x8 qf1a = *reinterpret_cast<const bf16x8*>(qpA + 32);
  bf16x8 qf0b = *reinterpret_cast<const bf16x8*>(qpB);
  bf16x8 qf1b = *reinterpret_cast<const bf16x8*>(qpB + 32);

  f32x4 oaccA[4] = {}, oaccB[4] = {};
  f32x4 lsumA = {}, lsumB = {};
  f32x4 zinitA = {}, zinitB = {};
  float mrowA = 0.f, mrowB = 0.f;
  bf16x8 bones;
#pragma unroll
  for (int e = 0; e < 8; ++e) bones[e] = (__bf16)1.0f;

  int c0 = wave, c1 = wave + 4;  // this wave's two 1KB chunks per buffer

#define STAGE(BUF, T)                                                        \
  do {                                                                       \
    const unsigned short* kg_ = KfH + (size_t)(T) * 4096;                    \
    const unsigned short* vg_ = VfH + (size_t)(T) * 4096;                    \
    gload_lds16(kg_ + c0 * 512 + lane * 8, &ldsK[BUF][c0 * 512]);            \
    gload_lds16(kg_ + c1 * 512 + lane * 8, &ldsK[BUF][c1 * 512]);            \
    gload_lds16(vg_ + c0 * 512 + lane * 8, &ldsV[BUF][c0 * 512]);            \
    gload_lds16(vg_ + c1 * 512 + lane * 8, &ldsV[BUF][c1 * 512]);            \
  } while (0)

// QK^T for one q-set: s[j] = K_frags x Qset + zinit (exp2 domain)
#define QK(SARR, QF0, QF1, ZI)                                                          \
  do {                                                                                  \
    _Pragma("unroll") for (int j_ = 0; j_ < 4; ++j_) {                                  \
      f32x4 z_ = ZI;                                                                    \
      z_ = __builtin_amdgcn_mfma_f32_16x16x32_bf16(kfr_[2 * j_], QF0, z_, 0, 0, 0);     \
      SARR[j_] = __builtin_amdgcn_mfma_f32_16x16x32_bf16(kfr_[2 * j_ + 1], QF1, z_, 0, 0, 0); \
    }                                                                                   \
  } while (0)

// softmax + PV for one q-set (defer-max THR=8; peeled FIRST establishes max)
#define SOFTPV(SARR, MROW, ZI, LSUM, OACC, FIRST)                                       \
  do {                                                                                  \
    float x1_ = fmaxf(fmaxf(SARR[0][0], SARR[0][1]), SARR[0][2]);                       \
    float x2_ = fmaxf(fmaxf(SARR[0][3], SARR[1][0]), SARR[1][1]);                       \
    float x3_ = fmaxf(fmaxf(SARR[1][2], SARR[1][3]), SARR[2][0]);                       \
    float x4_ = fmaxf(fmaxf(SARR[2][1], SARR[2][2]), SARR[2][3]);                       \
    float x5_ = fmaxf(fmaxf(SARR[3][0], SARR[3][1]), SARR[3][2]);                       \
    float pm_ = fmaxf(fmaxf(fmaxf(x1_, x2_), fmaxf(x3_, x4_)), fmaxf(x5_, SARR[3][3])); \
    pm_ = fmaxf(pm_, __shfl_xor(pm_, 16));                                              \
    pm_ = fmaxf(pm_, __shfl_xor(pm_, 32));                                              \
    if (FIRST) {                                                                        \
      _Pragma("unroll") for (int j_ = 0; j_ < 4; ++j_)                                  \
        _Pragma("unroll") for (int i_ = 0; i_ < 4; ++i_) SARR[j_][i_] -= pm_;           \
      MROW = pm_;                                                                       \
      ZI[0] = -MROW; ZI[1] = -MROW; ZI[2] = -MROW; ZI[3] = -MROW;                       \
    } else if (__any(pm_ > 8.f)) {                                                      \
      float dl_ = fmaxf(pm_, 0.f);                                                      \
      float al_ = EXP2(-dl_);                                                           \
      float a0_ = __shfl(al_, 20 * g + 0), a1_ = __shfl(al_, 20 * g + 1);               \
      float a2_ = __shfl(al_, 20 * g + 2), a3_ = __shfl(al_, 20 * g + 3);               \
      LSUM[0] *= a0_; LSUM[1] *= a1_; LSUM[2] *= a2_; LSUM[3] *= a3_;                   \
      _Pragma("unroll") for (int j_ = 0; j_ < 4; ++j_) {                                \
        OACC[j_][0] *= a0_; OACC[j_][1] *= a1_;                                         \
        OACC[j_][2] *= a2_; OACC[j_][3] *= a3_;                                         \
      }                                                                                 \
      _Pragma("unroll") for (int j_ = 0; j_ < 4; ++j_)                                  \
        _Pragma("unroll") for (int i_ = 0; i_ < 4; ++i_) SARR[j_][i_] -= dl_;           \
      MROW += dl_;                                                                      \
      ZI[0] = -MROW; ZI[1] = -MROW; ZI[2] = -MROW; ZI[3] = -MROW;                       \
    }                                                                                   \
    float p_[4][4];                                                                     \
    _Pragma("unroll") for (int j_ = 0; j_ < 4; ++j_)                                    \
      _Pragma("unroll") for (int i_ = 0; i_ < 4; ++i_)                                  \
        p_[j_][i_] = EXP2(SARR[j_][i_]);                                                \
    bf16x8 pa0_, pa1_;                                                                  \
    _Pragma("unroll") for (int e_ = 0; e_ < 8; ++e_) {                                  \
      pa0_[e_] = (__bf16)p_[2 * (e_ >> 2)][e_ & 3];                                     \
      pa1_[e_] = (__bf16)p_[1 + 2 * (e_ >> 2)][e_ & 3];                                 \
    }                                                                                   \
    LSUM = __builtin_amdgcn_mfma_f32_16x16x32_bf16(pa0_, bones, LSUM, 0, 0, 0);         \
    LSUM = __builtin_amdgcn_mfma_f32_16x16x32_bf16(pa1_, bones, LSUM, 0, 0, 0);         \
    _Pragma("unroll") for (int j_ = 0; j_ < 4; ++j_) {                                  \
      OACC[j_] = __builtin_amdgcn_mfma_f32_16x16x32_bf16(pa0_, vfr_[2 * j_], OACC[j_], 0, 0, 0); \
      OACC[j_] = __builtin_amdgcn_mfma_f32_16x16x32_bf16(pa1_, vfr_[2 * j_ + 1], OACC[j_], 0, 0, 0); \
    }                                                                                   \
  } while (0)

#define BODY(CUR, DO_STAGE, T, FIRSTF)                                                  \
  do {                                                                                  \
    __syncthreads(); /* buf[CUR] staged (own vmcnt drained); prev reads done */         \
    bf16x8 kfr_[8], vfr_[8];                                                            \
    _Pragma("unroll") for (int f_ = 0; f_ < 8; ++f_) {                                  \
      kfr_[f_] = *reinterpret_cast<const bf16x8*>(&ldsK[CUR][f_ * 512 + lane * 8]);     \
      vfr_[f_] = *reinterpret_cast<const bf16x8*>(&ldsV[CUR][f_ * 512 + lane * 8]);     \
    }                                                                                   \
    if (DO_STAGE) STAGE((CUR) ^ 1, (T) + 1);                                            \
    f32x4 sA_[4], sB_[4];                                                               \
    QK(sA_, qf0a, qf1a, zinitA);                                                        \
    QK(sB_, qf0b, qf1b, zinitB);                                                        \
    SOFTPV(sA_, mrowA, zinitA, lsumA, oaccA, FIRSTF);                                   \
    SOFTPV(sB_, mrowB, zinitB, lsumB, oaccB, FIRSTF);                                   \
  } while (0)

  STAGE(0, tb);
  BODY(0, true, tb, true);  // peeled first tile: establishes mrow exactly
  for (int pr = 0; pr < 15; ++pr) {
    BODY(1, true, tb + 2 * pr + 1, false);
    BODY(0, true, tb + 2 * pr + 2, false);
  }
  BODY(1, false, tb + 31, false);
#undef BODY
#undef SOFTPV
#undef QK
#undef STAGE

  // ---- epilogue: fp32 unnormalized partials + (l, m) per row
#pragma unroll
  for (int i = 0; i < 4; ++i) {
    int srowA = qbaseA + 4 * g + i;
    int srowB = qbaseB + 4 * g + i;
#pragma unroll
    for (int j = 0; j < 4; ++j) {
      int col = j * 16 + r16;
      OpH[(size_t)srowA * HDIM + col] = oaccA[j][i];
      OpH[(size_t)srowB * HDIM + col] = oaccB[j][i];
    }
  }
  if (g == 0) {  // m for rows qbase + r16 (per-lane running max)
    MpH[qbaseA + r16] = mrowA;
    MpH[qbaseB + r16] = mrowB;
  }
  if (r16 == 0) {  // l for rows qbase + 4g+i (lsum replicated across cols)
#pragma unroll
    for (int i = 0; i < 4; ++i) {
      LpH[qbaseA + 4 * g + i] = lsumA[i];
      LpH[qbaseB + 4 * g + i] = lsumB[i];
    }
  }
}

// ---------------------------------------------------------------------------
// Combine the two KV-half partials:
//   m = max(m0,m1); wi = exp2(mi - m); O = (o0*w0 + o1*w1)/(l0*w0 + l1*w1)
// Thread -> (h, s, 8 d's). Fully coalesced. Writes bf16 O[s][h*64+d].
// ---------------------------------------------------------------------------
__global__ __launch_bounds__(256) void k_combine(const float* __restrict__ Opart,
                                                 const float* __restrict__ Lpart,
                                                 const float* __restrict__ Mpart,
                                                 unsigned short* __restrict__ O) {
  int gidx = blockIdx.x * 256 + threadIdx.x;  // 12*4096*8 total
  int h = gidx >> 15;
  int rem = gidx & 32767;
  int s = rem >> 3;
  int d0 = (rem & 7) * 8;
  size_t i0 = (size_t)h * S_LEN + s;
  size_t o0 = i0 * HDIM + d0;
  const size_t HS_O = (size_t)NHEAD * S_LEN * HDIM;
  const size_t HS_L = (size_t)NHEAD * S_LEN;

  float m0 = Mpart[i0], m1 = Mpart[HS_L + i0];
  float l0 = Lpart[i0], l1 = Lpart[HS_L + i0];
  float m = fmaxf(m0, m1);
  float w0 = EXP2(m0 - m), w1 = EXP2(m1 - m);
  float inv = 1.0f / (l0 * w0 + l1 * w1);
  float4 a0 = *reinterpret_cast<const float4*>(Opart + o0);
  float4 a1 = *reinterpret_cast<const float4*>(Opart + o0 + 4);
  float4 b0 = *reinterpret_cast<const float4*>(Opart + HS_O + o0);
  float4 b1 = *reinterpret_cast<const float4*>(Opart + HS_O + o0 + 4);
  ushort8 r;
  r[0] = f2bf((a0.x * w0 + b0.x * w1) * inv);
  r[1] = f2bf((a0.y * w0 + b0.y * w1) * inv);
  r[2] = f2bf((a0.z * w0 + b0.z * w1) * inv);
  r[3] = f2bf((a0.w * w0 + b0.w * w1) * inv);
  r[4] = f2bf((a1.x * w0 + b1.x * w1) * inv);
  r[5] = f2bf((a1.y * w0 + b1.y * w1) * inv);
  r[6] = f2bf((a1.z * w0 + b1.z * w1) * inv);
  r[7] = f2bf((a1.w * w0 + b1.w * w1) * inv);
  *reinterpret_cast<ushort8*>(O + (size_t)s * DMODEL + h * HDIM + d0) = r;
}

// ---------------------------------------------------------------------------
extern "C" void kernel_launch(void* const* d_in, const int* in_sizes, int n_in,
                              void* d_out, int out_size, void* d_ws, size_t ws_size,
                              hipStream_t stream) {
  const float* x = (const float*)d_in[0];       // [4096][768]
  const float* w_qkv = (const float*)d_in[1];   // [768][2304]
  const float* b_qkv = (const float*)d_in[2];   // [2304]
  const float* w_proj = (const float*)d_in[3];  // [768][768]
  const float* b_proj = (const float*)d_in[4];  // [768]
  float* out = (float*)d_out;                   // [4096][768]

  unsigned short* ws16 = (unsigned short*)d_ws;
  unsigned short* xb = ws16;                                   // 4096*768
  unsigned short* wqkvT = xb + (size_t)S_LEN * DMODEL;         // 2304*768
  unsigned short* wprojT = wqkvT + (size_t)DQKV * DMODEL;      // 768*768
  unsigned short* Qb = wprojT + (size_t)DMODEL * DMODEL;       // 12*4096*64
  unsigned short* Kf = Qb + (size_t)NHEAD * S_LEN * HDIM;
  unsigned short* Vf = Kf + (size_t)NHEAD * S_LEN * HDIM;
  float* Opart = (float*)(Vf + (size_t)NHEAD * S_LEN * HDIM);  // 2*12*4096*64 f32
  float* Lpart = Opart + (size_t)2 * NHEAD * S_LEN * HDIM;     // 2*12*4096 f32
  float* Mpart = Lpart + (size_t)2 * NHEAD * S_LEN;            // 2*12*4096 f32
  unsigned short* Ob = xb;  // alias: x dead after QKV GEMM

  // 1) convert x
  k_convert<<<(S_LEN * DMODEL) / (256 * 8), 256, 0, stream>>>(x, xb, S_LEN * DMODEL);
  // 2) transpose-convert weights to [N][K] bf16
  k_transpose<<<dim3(DQKV / 64, DMODEL / 64), 256, 0, stream>>>(w_qkv, wqkvT, DMODEL, DQKV);
  k_transpose<<<dim3(DMODEL / 64, DMODEL / 64), 256, 0, stream>>>(w_proj, wprojT, DMODEL, DMODEL);
  // 3) QKV GEMM + fragment-linear scatter
  k_gemm<0><<<dim3(DQKV / 128, S_LEN / 128), 256, 0, stream>>>(xb, wqkvT, b_qkv, Qb, Kf, Vf, nullptr);
  // 4) attention, KV-split x2 (768 blocks, XCD-remapped in-kernel)
  k_attn<<<768, 256, 0, stream>>>(Qb, Kf, Vf, Opart, Lpart, Mpart);
  // 4b) combine halves -> Ob (bf16)
  k_combine<<<(NHEAD * S_LEN * 8) / 256, 256, 0, stream>>>(Opart, Lpart, Mpart, Ob);
  // 5) output projection
  k_gemm<1><<<dim3(DMODEL / 128, S_LEN / 128), 256, 0, stream>>>(Ob, wprojT, b_proj, nullptr, nullptr, nullptr, out);
}

// Round 11
// 126.589 us; speedup vs baseline: 1.2577x; 1.0365x over previous
//
#include <hip/hip_runtime.h>

// Problem constants
#define S_LEN 4096
#define DMODEL 768
#define NHEAD 12
#define HDIM 64
#define DQKV 2304

typedef __attribute__((ext_vector_type(8))) __bf16 bf16x8;
typedef __attribute__((ext_vector_type(4))) float f32x4;
typedef __attribute__((ext_vector_type(8))) unsigned short ushort8;

#define LOG2E 1.4426950408889634f

#if __has_builtin(__builtin_amdgcn_exp2f)
#define EXP2(x) __builtin_amdgcn_exp2f(x)
#else
#define EXP2(x) exp2f(x)
#endif

static __device__ __forceinline__ unsigned short f2bf(float f) {
  unsigned int u = __float_as_uint(f);
  u += 0x7FFFu + ((u >> 16) & 1u);  // round-to-nearest-even
  return (unsigned short)(u >> 16);
}

// async global -> LDS, 16B per lane. Dest must be wave-uniform; HW writes
// lptr + lane*16. Global src is per-lane (contiguous here -> coalesced).
static __device__ __forceinline__ void gload_lds16(const unsigned short* g, unsigned short* l) {
  __builtin_amdgcn_global_load_lds(
      (const __attribute__((address_space(1))) unsigned int*)g,
      (__attribute__((address_space(3))) unsigned int*)l, 16, 0, 0);
}

// ---------------------------------------------------------------------------
// Merged prep kernel (one launch instead of three):
//  blocks [0,1536):        fp32->bf16 convert of x
//  blocks [1536,1968):     w_qkv [768][2304] -> [2304][768] bf16 transpose
//  blocks [1968,2112):     w_proj [768][768] -> [768][768] bf16 transpose
// ---------------------------------------------------------------------------
__global__ __launch_bounds__(256) void k_prep(const float* __restrict__ x,
                                              const float* __restrict__ w_qkv,
                                              const float* __restrict__ w_proj,
                                              unsigned short* __restrict__ xb,
                                              unsigned short* __restrict__ wqkvT,
                                              unsigned short* __restrict__ wprojT) {
  __shared__ unsigned short t[64 * 65];
  int bid = blockIdx.x;
  int tid = threadIdx.x;
  if (bid < 1536) {
    int i = (bid * 256 + tid) * 8;
    const float4* p = reinterpret_cast<const float4*>(x + i);
    float4 a = p[0], b = p[1];
    ushort8 r;
    r[0] = f2bf(a.x); r[1] = f2bf(a.y); r[2] = f2bf(a.z); r[3] = f2bf(a.w);
    r[4] = f2bf(b.x); r[5] = f2bf(b.y); r[6] = f2bf(b.z); r[7] = f2bf(b.w);
    *reinterpret_cast<ushort8*>(xb + i) = r;
    return;
  }
  const float* in;
  unsigned short* out;
  int Kdim, Ndim, bx, by;
  if (bid < 1968) {
    int tt = bid - 1536;
    in = w_qkv; out = wqkvT; Kdim = DMODEL; Ndim = DQKV;
    bx = tt % 36; by = tt / 36;
  } else {
    int tt = bid - 1968;
    in = w_proj; out = wprojT; Kdim = DMODEL; Ndim = DMODEL;
    bx = tt % 12; by = tt / 12;
  }
  int k0 = by * 64, n0 = bx * 64;
#pragma unroll
  for (int p = 0; p < 4; ++p) {
    int r = p * 16 + (tid >> 4);
    int c = (tid & 15) * 4;
    float4 v = *reinterpret_cast<const float4*>(in + (size_t)(k0 + r) * Ndim + n0 + c);
    t[(c + 0) * 65 + r] = f2bf(v.x);
    t[(c + 1) * 65 + r] = f2bf(v.y);
    t[(c + 2) * 65 + r] = f2bf(v.z);
    t[(c + 3) * 65 + r] = f2bf(v.w);
  }
  __syncthreads();
#pragma unroll
  for (int p = 0; p < 2; ++p) {
    int task = p * 256 + tid;
    int rr = task >> 3;
    int cc = (task & 7) * 8;
    ushort8 r;
#pragma unroll
    for (int j = 0; j < 8; ++j) r[j] = t[rr * 65 + cc + j];
    *reinterpret_cast<ushort8*>(out + (size_t)(n0 + rr) * Kdim + k0 + cc) = r;
  }
}

// ---------------------------------------------------------------------------
// QKV GEMM: C[4096][2304] = A[4096][768] * Bt[2304][768]^T, 128x128 tiles,
// BK=32, 4 waves 4x4 frags. gload_lds staging, double-buffered, 1 barrier
// per K-step. Epilogue scatters Q (scaled), K/V fragment-linear.
// ---------------------------------------------------------------------------
__global__ __launch_bounds__(256) void k_gemm_qkv(const unsigned short* __restrict__ A,
                                                  const unsigned short* __restrict__ Bt,
                                                  const float* __restrict__ bias,
                                                  unsigned short* __restrict__ Qb,
                                                  unsigned short* __restrict__ Kf,
                                                  unsigned short* __restrict__ Vf) {
  __shared__ unsigned short As[2][128 * 32];
  __shared__ unsigned short Bs[2][128 * 32];

  int tid = threadIdx.x;
  int lane = tid & 63, wave = tid >> 6;
  int wr = wave >> 1, wc = wave & 1;
  int m0 = blockIdx.y * 128, n0 = blockIdx.x * 128;
  int r16 = lane & 15, g = lane >> 4;

  int ca0 = wave * 2, ca1 = wave * 2 + 1;
  int srow = lane >> 2, scol = (lane & 3) * 8;

  f32x4 acc[4][4] = {};

#define GSTAGE(BUF, K0)                                                                 \
  do {                                                                                  \
    gload_lds16(A + (size_t)(m0 + ca0 * 16 + srow) * DMODEL + (K0) + scol,              \
                &As[BUF][ca0 * 512]);                                                   \
    gload_lds16(A + (size_t)(m0 + ca1 * 16 + srow) * DMODEL + (K0) + scol,              \
                &As[BUF][ca1 * 512]);                                                   \
    gload_lds16(Bt + (size_t)(n0 + ca0 * 16 + srow) * DMODEL + (K0) + scol,             \
                &Bs[BUF][ca0 * 512]);                                                   \
    gload_lds16(Bt + (size_t)(n0 + ca1 * 16 + srow) * DMODEL + (K0) + scol,             \
                &Bs[BUF][ca1 * 512]);                                                   \
  } while (0)

  GSTAGE(0, 0);
  for (int kt = 0; kt < DMODEL / 32; ++kt) {
    int cur = kt & 1;
    __syncthreads();

    bf16x8 af[4], bfr[4];
#pragma unroll
    for (int m = 0; m < 4; ++m)
      af[m] = *reinterpret_cast<const bf16x8*>(&As[cur][(wr * 64 + m * 16 + r16) * 32 + g * 8]);
#pragma unroll
    for (int n = 0; n < 4; ++n)
      bfr[n] = *reinterpret_cast<const bf16x8*>(&Bs[cur][(wc * 64 + n * 16 + r16) * 32 + g * 8]);

    if (kt < DMODEL / 32 - 1) GSTAGE(cur ^ 1, (kt + 1) * 32);

#pragma unroll
    for (int m = 0; m < 4; ++m)
#pragma unroll
      for (int n = 0; n < 4; ++n)
        acc[m][n] = __builtin_amdgcn_mfma_f32_16x16x32_bf16(af[m], bfr[n], acc[m][n], 0, 0, 0);
  }
#undef GSTAGE

  // Epilogue. C/D layout: col = lane&15, row = 4*(lane>>4) + reg
#pragma unroll
  for (int m = 0; m < 4; ++m) {
    int grow0 = m0 + wr * 64 + m * 16 + 4 * g;
#pragma unroll
    for (int n = 0; n < 4; ++n) {
      int gcol = n0 + wc * 64 + n * 16 + r16;
      float bv = bias[gcol];
      int sect = gcol / DMODEL;
      int rem = gcol - sect * DMODEL;
      int h = rem >> 6, hd = rem & 63;
      if (sect == 2) {
        int j = hd >> 4, r16v = hd & 15;
        int tile = grow0 >> 6, kk = (grow0 >> 5) & 1, g2 = (grow0 >> 3) & 3, e0 = grow0 & 7;
        size_t base = (((size_t)h * 64 + tile) * 8 + (j * 2 + kk)) * 512 +
                      (size_t)(g2 * 16 + r16v) * 8 + e0;
        ushort4 pk;
        pk.x = f2bf(acc[m][n][0] + bv);
        pk.y = f2bf(acc[m][n][1] + bv);
        pk.z = f2bf(acc[m][n][2] + bv);
        pk.w = f2bf(acc[m][n][3] + bv);
        *reinterpret_cast<ushort4*>(Vf + base) = pk;
      } else if (sect == 0) {
#pragma unroll
        for (int i = 0; i < 4; ++i)
          Qb[((size_t)h * S_LEN + grow0 + i) * HDIM + hd] =
              f2bf((acc[m][n][i] + bv) * (0.125f * LOG2E));
      } else {
        int kk = hd >> 5, g2 = (hd >> 3) & 3, e = hd & 7;
#pragma unroll
        for (int i = 0; i < 4; ++i) {
          int s = grow0 + i;
          int tile = s >> 6, r = s & 63;
          int j = (((r >> 2) & 1) << 1) | (r >> 5);
          int r16l = (r & 3) | (((r >> 3) & 3) << 2);
          size_t idx = (((size_t)h * 64 + tile) * 8 + (j * 2 + kk)) * 512 +
                       (size_t)(g2 * 16 + r16l) * 8 + e;
          Kf[idx] = f2bf(acc[m][n][i] + bv);
        }
      }
    }
  }
}

// ---------------------------------------------------------------------------
// Output projection GEMM: out[4096][768] = Ob[4096][768] * wprojT^T + bias.
// 64x64 tiles -> grid 12x64 = 768 blocks = 3/CU, perfectly balanced.
// 4 waves, each 32x32 (2x2 frags). Same 1-barrier staged loop.
// ---------------------------------------------------------------------------
__global__ __launch_bounds__(256) void k_gemm_proj(const unsigned short* __restrict__ A,
                                                   const unsigned short* __restrict__ Bt,
                                                   const float* __restrict__ bias,
                                                   float* __restrict__ outf) {
  __shared__ unsigned short As[2][64 * 32];
  __shared__ unsigned short Bs[2][64 * 32];

  int tid = threadIdx.x;
  int lane = tid & 63, wave = tid >> 6;
  int wr = wave >> 1, wc = wave & 1;
  int m0 = blockIdx.y * 64, n0 = blockIdx.x * 64;
  int r16 = lane & 15, g = lane >> 4;
  int srow = lane >> 2, scol = (lane & 3) * 8;

  f32x4 acc[2][2] = {};

#define GSTAGE(BUF, K0)                                                                 \
  do {                                                                                  \
    gload_lds16(A + (size_t)(m0 + wave * 16 + srow) * DMODEL + (K0) + scol,             \
                &As[BUF][wave * 512]);                                                  \
    gload_lds16(Bt + (size_t)(n0 + wave * 16 + srow) * DMODEL + (K0) + scol,            \
                &Bs[BUF][wave * 512]);                                                  \
  } while (0)

  GSTAGE(0, 0);
  for (int kt = 0; kt < DMODEL / 32; ++kt) {
    int cur = kt & 1;
    __syncthreads();

    bf16x8 af[2], bfr[2];
#pragma unroll
    for (int m = 0; m < 2; ++m)
      af[m] = *reinterpret_cast<const bf16x8*>(&As[cur][(wr * 32 + m * 16 + r16) * 32 + g * 8]);
#pragma unroll
    for (int n = 0; n < 2; ++n)
      bfr[n] = *reinterpret_cast<const bf16x8*>(&Bs[cur][(wc * 32 + n * 16 + r16) * 32 + g * 8]);

    if (kt < DMODEL / 32 - 1) GSTAGE(cur ^ 1, (kt + 1) * 32);

#pragma unroll
    for (int m = 0; m < 2; ++m)
#pragma unroll
      for (int n = 0; n < 2; ++n)
        acc[m][n] = __builtin_amdgcn_mfma_f32_16x16x32_bf16(af[m], bfr[n], acc[m][n], 0, 0, 0);
  }
#undef GSTAGE

#pragma unroll
  for (int m = 0; m < 2; ++m) {
    int grow0 = m0 + wr * 32 + m * 16 + 4 * g;
#pragma unroll
    for (int n = 0; n < 2; ++n) {
      int gcol = n0 + wc * 32 + n * 16 + r16;
      float bv = bias[gcol];
#pragma unroll
      for (int i = 0; i < 4; ++i)
        outf[(size_t)(grow0 + i) * DMODEL + gcol] = acc[m][n][i] + bv;
    }
  }
}

// ---------------------------------------------------------------------------
// Flash attention, KV-SPLIT x4: grid 1536 = 12 heads x 32 q-blocks(128 rows)
// x 4 KV-quarters -> 5 blocks/CU resident (LDS-capped), ~20 waves/CU TLP.
// 4 waves/block x 32 q-rows (two 16-row sets A/B). Each block handles 16 KV
// tiles, writes fp32 unnormalized partials (O', l, m); k_combine merges 4.
// Numerics per quarter = proven R7 path (peeled first tile, defer-max THR=8,
// zinit C-seed, ones-MFMA l, exp2 domain).
// ---------------------------------------------------------------------------
__global__ __launch_bounds__(256, 3) void k_attn(const unsigned short* __restrict__ Q,
                                                 const unsigned short* __restrict__ Kf,
                                                 const unsigned short* __restrict__ Vf,
                                                 float* __restrict__ Opart,
                                                 float* __restrict__ Lpart,
                                                 float* __restrict__ Mpart) {
  __shared__ unsigned short ldsK[2][4096];
  __shared__ unsigned short ldsV[2][4096];

  int tid = threadIdx.x;
  int lane = tid & 63, wave = tid >> 6;
  int r16 = lane & 15, g = lane >> 4;

  // XCD-aware remap (bijective on 0..1535); consecutive gids share a head
  int bid = blockIdx.x;
  int gid = (bid & 7) * 192 + (bid >> 3);
  int h = gid >> 7;            // head
  int rem = gid & 127;
  int quarter = rem & 3;       // KV quarter
  int qb = rem >> 2;           // q-block (128 rows)
  int qbaseA = qb * 128 + wave * 16;
  int qbaseB = qbaseA + 64;
  int tb = quarter * 16;       // first tile of this quarter

  const unsigned short* KfH = Kf + (size_t)h * (64 * 4096);
  const unsigned short* VfH = Vf + (size_t)h * (64 * 4096);
  float* OpH = Opart + ((size_t)quarter * NHEAD + h) * S_LEN * HDIM;
  float* LpH = Lpart + ((size_t)quarter * NHEAD + h) * S_LEN;
  float* MpH = Mpart + ((size_t)quarter * NHEAD + h) * S_LEN;

  const unsigned short* qpA = Q + ((size_t)h * S_LEN + qbaseA + r16) * HDIM + g * 8;
  const unsigned short* qpB = Q + ((size_t)h * S_LEN + qbaseB + r16) * HDIM + g * 8;
  bf16x8 qf0a = *reinterpret_cast<const bf16x8*>(qpA);
  bf16x8 qf1a = *reinterpret_cast<const bf16x8*>(qpA + 32);
  bf16x8 qf0b = *reinterpret_cast<const bf16x8*>(qpB);
  bf16x8 qf1b = *reinterpret_cast<const bf16x8*>(qpB + 32);

  f32x4 oaccA[4] = {}, oaccB[4] = {};
  f32x4 lsumA = {}, lsumB = {};
  f32x4 zinitA = {}, zinitB = {};
  float mrowA = 0.f, mrowB = 0.f;
  bf16x8 bones;
#pragma unroll
  for (int e = 0; e < 8; ++e) bones[e] = (__bf16)1.0f;

  int c0 = wave, c1 = wave + 4;

#define STAGE(BUF, T)                                                        \
  do {                                                                       \
    const unsigned short* kg_ = KfH + (size_t)(T) * 4096;                    \
    const unsigned short* vg_ = VfH + (size_t)(T) * 4096;                    \
    gload_lds16(kg_ + c0 * 512 + lane * 8, &ldsK[BUF][c0 * 512]);            \
    gload_lds16(kg_ + c1 * 512 + lane * 8, &ldsK[BUF][c1 * 512]);            \
    gload_lds16(vg_ + c0 * 512 + lane * 8, &ldsV[BUF][c0 * 512]);            \
    gload_lds16(vg_ + c1 * 512 + lane * 8, &ldsV[BUF][c1 * 512]);            \
  } while (0)

#define QK(SARR, QF0, QF1, ZI)                                                          \
  do {                                                                                  \
    _Pragma("unroll") for (int j_ = 0; j_ < 4; ++j_) {                                  \
      f32x4 z_ = ZI;                                                                    \
      z_ = __builtin_amdgcn_mfma_f32_16x16x32_bf16(kfr_[2 * j_], QF0, z_, 0, 0, 0);     \
      SARR[j_] = __builtin_amdgcn_mfma_f32_16x16x32_bf16(kfr_[2 * j_ + 1], QF1, z_, 0, 0, 0); \
    }                                                                                   \
  } while (0)

#define SOFTPV(SARR, MROW, ZI, LSUM, OACC, FIRST)                                       \
  do {                                                                                  \
    float x1_ = fmaxf(fmaxf(SARR[0][0], SARR[0][1]), SARR[0][2]);                       \
    float x2_ = fmaxf(fmaxf(SARR[0][3], SARR[1][0]), SARR[1][1]);                       \
    float x3_ = fmaxf(fmaxf(SARR[1][2], SARR[1][3]), SARR[2][0]);                       \
    float x4_ = fmaxf(fmaxf(SARR[2][1], SARR[2][2]), SARR[2][3]);                       \
    float x5_ = fmaxf(fmaxf(SARR[3][0], SARR[3][1]), SARR[3][2]);                       \
    float pm_ = fmaxf(fmaxf(fmaxf(x1_, x2_), fmaxf(x3_, x4_)), fmaxf(x5_, SARR[3][3])); \
    pm_ = fmaxf(pm_, __shfl_xor(pm_, 16));                                              \
    pm_ = fmaxf(pm_, __shfl_xor(pm_, 32));                                              \
    if (FIRST) {                                                                        \
      _Pragma("unroll") for (int j_ = 0; j_ < 4; ++j_)                                  \
        _Pragma("unroll") for (int i_ = 0; i_ < 4; ++i_) SARR[j_][i_] -= pm_;           \
      MROW = pm_;                                                                       \
      ZI[0] = -MROW; ZI[1] = -MROW; ZI[2] = -MROW; ZI[3] = -MROW;                       \
    } else if (__any(pm_ > 8.f)) {                                                      \
      float dl_ = fmaxf(pm_, 0.f);                                                      \
      float al_ = EXP2(-dl_);                                                           \
      float a0_ = __shfl(al_, 20 * g + 0), a1_ = __shfl(al_, 20 * g + 1);               \
      float a2_ = __shfl(al_, 20 * g + 2), a3_ = __shfl(al_, 20 * g + 3);               \
      LSUM[0] *= a0_; LSUM[1] *= a1_; LSUM[2] *= a2_; LSUM[3] *= a3_;                   \
      _Pragma("unroll") for (int j_ = 0; j_ < 4; ++j_) {                                \
        OACC[j_][0] *= a0_; OACC[j_][1] *= a1_;                                         \
        OACC[j_][2] *= a2_; OACC[j_][3] *= a3_;                                         \
      }                                                                                 \
      _Pragma("unroll") for (int j_ = 0; j_ < 4; ++j_)                                  \
        _Pragma("unroll") for (int i_ = 0; i_ < 4; ++i_) SARR[j_][i_] -= dl_;           \
      MROW += dl_;                                                                      \
      ZI[0] = -MROW; ZI[1] = -MROW; ZI[2] = -MROW; ZI[3] = -MROW;                       \
    }                                                                                   \
    float p_[4][4];                                                                     \
    _Pragma("unroll") for (int j_ = 0; j_ < 4; ++j_)                                    \
      _Pragma("unroll") for (int i_ = 0; i_ < 4; ++i_)                                  \
        p_[j_][i_] = EXP2(SARR[j_][i_]);                                                \
    bf16x8 pa0_, pa1_;                                                                  \
    _Pragma("unroll") for (int e_ = 0; e_ < 8; ++e_) {                                  \
      pa0_[e_] = (__bf16)p_[2 * (e_ >> 2)][e_ & 3];                                     \
      pa1_[e_] = (__bf16)p_[1 + 2 * (e_ >> 2)][e_ & 3];                                 \
    }                                                                                   \
    LSUM = __builtin_amdgcn_mfma_f32_16x16x32_bf16(pa0_, bones, LSUM, 0, 0, 0);         \
    LSUM = __builtin_amdgcn_mfma_f32_16x16x32_bf16(pa1_, bones, LSUM, 0, 0, 0);         \
    _Pragma("unroll") for (int j_ = 0; j_ < 4; ++j_) {                                  \
      OACC[j_] = __builtin_amdgcn_mfma_f32_16x16x32_bf16(pa0_, vfr_[2 * j_], OACC[j_], 0, 0, 0); \
      OACC[j_] = __builtin_amdgcn_mfma_f32_16x16x32_bf16(pa1_, vfr_[2 * j_ + 1], OACC[j_], 0, 0, 0); \
    }                                                                                   \
  } while (0)

#define BODY(CUR, DO_STAGE, T, FIRSTF)                                                  \
  do {                                                                                  \
    __syncthreads();                                                                    \
    bf16x8 kfr_[8], vfr_[8];                                                            \
    _Pragma("unroll") for (int f_ = 0; f_ < 8; ++f_) {                                  \
      kfr_[f_] = *reinterpret_cast<const bf16x8*>(&ldsK[CUR][f_ * 512 + lane * 8]);     \
      vfr_[f_] = *reinterpret_cast<const bf16x8*>(&ldsV[CUR][f_ * 512 + lane * 8]);     \
    }                                                                                   \
    if (DO_STAGE) STAGE((CUR) ^ 1, (T) + 1);                                            \
    f32x4 sA_[4], sB_[4];                                                               \
    QK(sA_, qf0a, qf1a, zinitA);                                                        \
    QK(sB_, qf0b, qf1b, zinitB);                                                        \
    SOFTPV(sA_, mrowA, zinitA, lsumA, oaccA, FIRSTF);                                   \
    SOFTPV(sB_, mrowB, zinitB, lsumB, oaccB, FIRSTF);                                   \
  } while (0)

  STAGE(0, tb);
  BODY(0, true, tb, true);
  for (int pr = 0; pr < 7; ++pr) {
    BODY(1, true, tb + 2 * pr + 1, false);
    BODY(0, true, tb + 2 * pr + 2, false);
  }
  BODY(1, false, tb + 15, false);
#undef BODY
#undef SOFTPV
#undef QK
#undef STAGE

  // epilogue: fp32 unnormalized partials + (l, m) per row
#pragma unroll
  for (int i = 0; i < 4; ++i) {
    int srowA = qbaseA + 4 * g + i;
    int srowB = qbaseB + 4 * g + i;
#pragma unroll
    for (int j = 0; j < 4; ++j) {
      int col = j * 16 + r16;
      OpH[(size_t)srowA * HDIM + col] = oaccA[j][i];
      OpH[(size_t)srowB * HDIM + col] = oaccB[j][i];
    }
  }
  if (g == 0) {
    MpH[qbaseA + r16] = mrowA;
    MpH[qbaseB + r16] = mrowB;
  }
  if (r16 == 0) {
#pragma unroll
    for (int i = 0; i < 4; ++i) {
      LpH[qbaseA + 4 * g + i] = lsumA[i];
      LpH[qbaseB + 4 * g + i] = lsumB[i];
    }
  }
}

// ---------------------------------------------------------------------------
// Combine 4 KV-quarter partials:
//   m = max_i m_i; w_i = exp2(m_i - m); O = sum(o_i w_i) / sum(l_i w_i)
// ---------------------------------------------------------------------------
__global__ __launch_bounds__(256) void k_combine(const float* __restrict__ Opart,
                                                 const float* __restrict__ Lpart,
                                                 const float* __restrict__ Mpart,
                                                 unsigned short* __restrict__ O) {
  int gidx = blockIdx.x * 256 + threadIdx.x;  // 12*4096*8 total
  int h = gidx >> 15;
  int rem = gidx & 32767;
  int s = rem >> 3;
  int d0 = (rem & 7) * 8;
  size_t i0 = (size_t)h * S_LEN + s;
  size_t o0 = i0 * HDIM + d0;
  const size_t HS_O = (size_t)NHEAD * S_LEN * HDIM;
  const size_t HS_L = (size_t)NHEAD * S_LEN;

  float m0 = Mpart[i0], m1 = Mpart[HS_L + i0];
  float m2 = Mpart[2 * HS_L + i0], m3 = Mpart[3 * HS_L + i0];
  float l0 = Lpart[i0], l1 = Lpart[HS_L + i0];
  float l2 = Lpart[2 * HS_L + i0], l3 = Lpart[3 * HS_L + i0];
  float m = fmaxf(fmaxf(m0, m1), fmaxf(m2, m3));
  float w0 = EXP2(m0 - m), w1 = EXP2(m1 - m), w2 = EXP2(m2 - m), w3 = EXP2(m3 - m);
  float inv = 1.0f / (l0 * w0 + l1 * w1 + l2 * w2 + l3 * w3);

  float acc[8];
#pragma unroll
  for (int q = 0; q < 4; ++q) {
    float w = (q == 0) ? w0 : (q == 1) ? w1 : (q == 2) ? w2 : w3;
    const float* src = Opart + q * HS_O + o0;
    float4 a = *reinterpret_cast<const float4*>(src);
    float4 b = *reinterpret_cast<const float4*>(src + 4);
    if (q == 0) {
      acc[0] = a.x * w; acc[1] = a.y * w; acc[2] = a.z * w; acc[3] = a.w * w;
      acc[4] = b.x * w; acc[5] = b.y * w; acc[6] = b.z * w; acc[7] = b.w * w;
    } else {
      acc[0] += a.x * w; acc[1] += a.y * w; acc[2] += a.z * w; acc[3] += a.w * w;
      acc[4] += b.x * w; acc[5] += b.y * w; acc[6] += b.z * w; acc[7] += b.w * w;
    }
  }
  ushort8 r;
#pragma unroll
  for (int e = 0; e < 8; ++e) r[e] = f2bf(acc[e] * inv);
  *reinterpret_cast<ushort8*>(O + (size_t)s * DMODEL + h * HDIM + d0) = r;
}

// ---------------------------------------------------------------------------
extern "C" void kernel_launch(void* const* d_in, const int* in_sizes, int n_in,
                              void* d_out, int out_size, void* d_ws, size_t ws_size,
                              hipStream_t stream) {
  const float* x = (const float*)d_in[0];       // [4096][768]
  const float* w_qkv = (const float*)d_in[1];   // [768][2304]
  const float* b_qkv = (const float*)d_in[2];   // [2304]
  const float* w_proj = (const float*)d_in[3];  // [768][768]
  const float* b_proj = (const float*)d_in[4];  // [768]
  float* out = (float*)d_out;                   // [4096][768]

  unsigned short* ws16 = (unsigned short*)d_ws;
  unsigned short* xb = ws16;                                   // 4096*768
  unsigned short* wqkvT = xb + (size_t)S_LEN * DMODEL;         // 2304*768
  unsigned short* wprojT = wqkvT + (size_t)DQKV * DMODEL;      // 768*768
  unsigned short* Qb = wprojT + (size_t)DMODEL * DMODEL;       // 12*4096*64
  unsigned short* Kf = Qb + (size_t)NHEAD * S_LEN * HDIM;
  unsigned short* Vf = Kf + (size_t)NHEAD * S_LEN * HDIM;
  float* Opart = (float*)(Vf + (size_t)NHEAD * S_LEN * HDIM);  // 4*12*4096*64 f32
  float* Lpart = Opart + (size_t)4 * NHEAD * S_LEN * HDIM;     // 4*12*4096 f32
  float* Mpart = Lpart + (size_t)4 * NHEAD * S_LEN;            // 4*12*4096 f32
  unsigned short* Ob = xb;  // alias: x dead after QKV GEMM

  // 1) merged prep: convert x + transpose both weights
  k_prep<<<2112, 256, 0, stream>>>(x, w_qkv, w_proj, xb, wqkvT, wprojT);
  // 2) QKV GEMM + fragment-linear scatter
  k_gemm_qkv<<<dim3(DQKV / 128, S_LEN / 128), 256, 0, stream>>>(xb, wqkvT, b_qkv, Qb, Kf, Vf);
  // 3) attention, KV-split x4 (1536 blocks, XCD-remapped in-kernel)
  k_attn<<<1536, 256, 0, stream>>>(Qb, Kf, Vf, Opart, Lpart, Mpart);
  // 3b) combine quarters -> Ob (bf16)
  k_combine<<<(NHEAD * S_LEN * 8) / 256, 256, 0, stream>>>(Opart, Lpart, Mpart, Ob);
  // 4) output projection (64x64 tiles, 768 balanced blocks)
  k_gemm_proj<<<dim3(DMODEL / 64, S_LEN / 64), 256, 0, stream>>>(Ob, wprojT, b_proj, out);
}